// Round 12
// baseline (373.188 us; speedup 1.0000x reference)
//
#include <hip/hip_runtime.h>

// MultiHeadedAttention with relative position (B=2, T=1024, D=1024, H=16, DK=64)
// Pipeline: cvt(inputs->bf16), wtrans(W->bf16 [n][k]) -> fused QKV GEMM (XCD-swizzled) ->
//   k_qk: S = q@k^T (raw, bf16) ->
//   k_posk_pv: S = exp(S + Bp + bias - 10) in place (masked->0) AND
//              X0f += eS @ pos_v[t, s-strip]  (fp32 global atomics, X0f pre-zeroed) ->
//   X = (X0f + eS@v)/l (l inline) -> out = X@Wo+bo.
// softmax(s)@V == (exp(s-c)@V)/sum(exp(s-c)).

#define DEV __device__ __forceinline__

typedef short bf16x8 __attribute__((ext_vector_type(8)));
typedef short bf16x4 __attribute__((ext_vector_type(4)));
typedef float f32x4 __attribute__((ext_vector_type(4)));

DEV short f2b(float f) {
  unsigned u = __builtin_bit_cast(unsigned, f);
  u = (u + 0x7FFFu + ((u >> 16) & 1u)) >> 16;
  return (short)u;
}
DEV float b2f(short s) {
  unsigned u = ((unsigned)(unsigned short)s) << 16;
  return __builtin_bit_cast(float, u);
}

#define MFMA(a, b, c) __builtin_amdgcn_mfma_f32_16x16x32_bf16(a, b, c, 0, 0, 0)

DEV void gload16(const void* g, void* l) {
  __builtin_amdgcn_global_load_lds(
      (const __attribute__((address_space(1))) void*)g,
      (__attribute__((address_space(3))) void*)l, 16, 0, 0);
}

// ---------------------------------------------------------------------------
// P1: fp32 -> bf16 flat convert for query/key/value.
__global__ __launch_bounds__(256) void k_cvt3(
    const float* __restrict__ a, const float* __restrict__ b, const float* __restrict__ c,
    short* __restrict__ oa, short* __restrict__ ob, short* __restrict__ oc) {
  const float* src = blockIdx.y == 0 ? a : (blockIdx.y == 1 ? b : c);
  short* dst = blockIdx.y == 0 ? oa : (blockIdx.y == 1 ? ob : oc);
  size_t i = ((size_t)blockIdx.x * 256 + threadIdx.x) * 8;
  float4 p0 = *(const float4*)(src + i);
  float4 p1 = *(const float4*)(src + i + 4);
  bf16x8 o;
  o[0] = f2b(p0.x); o[1] = f2b(p0.y); o[2] = f2b(p0.z); o[3] = f2b(p0.w);
  o[4] = f2b(p1.x); o[5] = f2b(p1.y); o[6] = f2b(p1.z); o[7] = f2b(p1.w);
  *(bf16x8*)(dst + i) = o;
}

// P2: W [k][n] fp32 -> WT [n][k] bf16, 64x64 tiles via LDS.
__global__ __launch_bounds__(256) void k_wtrans4(
    const float* __restrict__ w0, const float* __restrict__ w1,
    const float* __restrict__ w2, const float* __restrict__ w3,
    short* __restrict__ o0, short* __restrict__ o1,
    short* __restrict__ o2, short* __restrict__ o3) {
  const float* src; short* dst;
  switch (blockIdx.z) {
    case 0: src = w0; dst = o0; break;
    case 1: src = w1; dst = o1; break;
    case 2: src = w2; dst = o2; break;
    default: src = w3; dst = o3;
  }
  __shared__ short LW[64][74];
  const int tid = threadIdx.x;
  const int k0 = blockIdx.y * 64, n0 = blockIdx.x * 64;
  {
    int c4 = (tid & 15) * 4;
#pragma unroll
    for (int i = 0; i < 4; ++i) {
      int r = (tid >> 4) + i * 16;
      float4 v = *(const float4*)(src + (size_t)(k0 + r) * 1024 + n0 + c4);
      LW[r][c4 + 0] = f2b(v.x); LW[r][c4 + 1] = f2b(v.y);
      LW[r][c4 + 2] = f2b(v.z); LW[r][c4 + 3] = f2b(v.w);
    }
  }
  __syncthreads();
  {
    int n = tid >> 2, kb = (tid & 3) * 16;
#pragma unroll
    for (int j2 = 0; j2 < 2; ++j2) {
      int kk = kb + j2 * 8;
      bf16x8 o;
#pragma unroll
      for (int j = 0; j < 8; ++j) o[j] = LW[kk + j][n];
      *(bf16x8*)(dst + (size_t)(n0 + n) * 1024 + k0 + kk) = o;
    }
  }
}

// ---------------------------------------------------------------------------
// K1: fused QKV projection with bijective XCD chunk-swizzle.
__global__ __launch_bounds__(256) void k_qkv(
    const short* __restrict__ Ain, const short* __restrict__ WT,
    const float* __restrict__ bq, const float* __restrict__ bk,
    const float* __restrict__ bv,
    short* __restrict__ qo, short* __restrict__ ko, short* __restrict__ vTo) {
  __shared__ short As[128 * 32];
  __shared__ short Bs[64 * 32];
  __shared__ short LW[128][72];
  const int tid = threadIdx.x;
  const int w = tid >> 6, l = tid & 63, lg = l >> 4, lr = l & 15;
  const int wm = w >> 1, wn = w & 1;
  const int flat = blockIdx.x + gridDim.x * blockIdx.y;  // 0..767
  const int flat2 = (flat & 7) * 96 + (flat >> 3);
  const int n0 = (flat2 & 15) * 64;
  const int m0 = (flat2 >> 4) * 128;
  const int seg = m0 >> 11;
  const int mseg = m0 & 2047;
  const short* Abase = Ain + ((size_t)m0 << 10);
  const short* Bbase = WT + ((size_t)seg << 20) + ((size_t)n0 << 10);
  const int srow = l >> 2, scol8 = (l & 3) * 8;
  f32x4 acc[4][2] = {};
  for (int k0 = 0; k0 < 1024; k0 += 32) {
    gload16(Abase + (size_t)((w * 2) * 16 + srow) * 1024 + k0 + scol8, &As[(w * 2) * 512]);
    gload16(Abase + (size_t)((w * 2 + 1) * 16 + srow) * 1024 + k0 + scol8, &As[(w * 2 + 1) * 512]);
    gload16(Bbase + (size_t)(w * 16 + srow) * 1024 + k0 + scol8, &Bs[w * 512]);
    __syncthreads();
    bf16x8 af[4], bf[2];
#pragma unroll
    for (int i = 0; i < 4; ++i) af[i] = *(const bf16x8*)&As[(wm * 64 + i * 16 + lr) * 32 + lg * 8];
#pragma unroll
    for (int i = 0; i < 2; ++i) bf[i] = *(const bf16x8*)&Bs[(wn * 32 + i * 16 + lr) * 32 + lg * 8];
#pragma unroll
    for (int mi = 0; mi < 4; ++mi)
#pragma unroll
      for (int ni = 0; ni < 2; ++ni) acc[mi][ni] = MFMA(af[mi], bf[ni], acc[mi][ni]);
    __syncthreads();
  }
  const float* bias = seg == 0 ? bq : (seg == 1 ? bk : bv);
  const float scale = seg == 0 ? 0.125f : 1.0f;
  float bvals[2];
#pragma unroll
  for (int ni = 0; ni < 2; ++ni) bvals[ni] = bias[n0 + wn * 32 + ni * 16 + lr];
#pragma unroll
  for (int mi = 0; mi < 4; ++mi)
#pragma unroll
    for (int ni = 0; ni < 2; ++ni)
#pragma unroll
      for (int r = 0; r < 4; ++r)
        LW[wm * 64 + mi * 16 + lg * 4 + r][wn * 32 + ni * 16 + lr] =
            f2b((acc[mi][ni][r] + bvals[ni]) * scale);
  __syncthreads();
  if (seg < 2) {
    short* dst = seg == 0 ? qo : ko;
    int r = tid >> 1, half = tid & 1;
    int m = mseg + r, b = m >> 10, t = m & 1023;
    int h = n0 >> 6;
#pragma unroll
    for (int g = 0; g < 4; ++g) {
      int dk = half * 32 + g * 8;
      bf16x8 o = *(const bf16x8*)&LW[r][dk];
      *(bf16x8*)(dst + (((size_t)(b * 16 + h) * 1024 + t) << 6) + dk) = o;
    }
  } else {
    int dkc = tid & 63, th = tid >> 6;
    int h = n0 >> 6, dk = dkc;
    int b = mseg >> 10;
    int tbase = (mseg & 1023) + th * 32;
#pragma unroll
    for (int g = 0; g < 4; ++g) {
      bf16x8 o;
#pragma unroll
      for (int e = 0; e < 8; ++e) o[e] = LW[th * 32 + g * 8 + e][dkc];
      *(bf16x8*)(vTo + (((size_t)(b * 16 + h) * 64 + dk) << 10) + tbase + g * 8) = o;
    }
  }
}

// ---------------------------------------------------------------------------
// K2a: S = q@k^T raw scores (bf16). grid (T/32, bh); 8 waves, wave 16t x 256s.
__global__ __launch_bounds__(512, 2) void k_qk(
    const short* __restrict__ q, const short* __restrict__ kmat,
    short* __restrict__ S) {
  const int bh = blockIdx.y;
  const int tid = threadIdx.x;
  const int w = tid >> 6, l = tid & 63, lg = l >> 4, lr = l & 15;
  const int wm = w >> 2, wn = w & 3;
  const int t0 = blockIdx.x * 32 + wm * 16;
  const int scol = wn * 256;
  __shared__ short LS[8][16][266];

  bf16x8 af[2];
#pragma unroll
  for (int kk = 0; kk < 2; ++kk)
    af[kk] = *(const bf16x8*)(q + ((size_t)bh * 1024 + (t0 + lr)) * 64 + kk * 32 + lg * 8);

#pragma unroll
  for (int ni = 0; ni < 16; ++ni) {
    int s = scol + ni * 16 + lr;
    const short* kp = kmat + ((size_t)bh * 1024 + s) * 64 + lg * 8;
    f32x4 a = {};
    a = MFMA(af[0], *(const bf16x8*)kp, a);
    a = MFMA(af[1], *(const bf16x8*)(kp + 32), a);
#pragma unroll
    for (int r = 0; r < 4; ++r) LS[w][lg * 4 + r][ni * 16 + lr] = f2b(a[r]);
  }
  short* sb = S + ((size_t)bh * 1024 + t0) * 1024 + scol;
  const int r2 = l >> 5, c16 = (l & 31) * 8;
#pragma unroll
  for (int rr = 0; rr < 8; ++rr) {
    int row = rr * 2 + r2;
    bf16x8 o = *(const bf16x8*)&LS[w][row][c16];
    *(bf16x8*)(sb + (size_t)row * 1024 + c16) = o;
  }
}

// ---------------------------------------------------------------------------
// K2b+K3 merged: per block (s-strip 128, t), 4 waves (32 s each):
//   S = exp(S + q.pos_k + bias - 10) in place (masked->0), then
//   X0f[bh, t, dk] += eS(32s) @ pos_v[t, 32s, dk]  via fp32 global atomics.
// One barrier (RB/MK cross-wave); SW/pvT are per-wave.
__global__ __launch_bounds__(256) void k_posk_pv(
    const short* __restrict__ q, const float* __restrict__ pos_k,
    const float* __restrict__ pos_v, const float* __restrict__ rab,
    const int* __restrict__ mask, short* __restrict__ S,
    float* __restrict__ X0f) {
  const int t = blockIdx.y;
  const int tid = threadIdx.x;
  const int w = tid >> 6, l = tid & 63, lg = l >> 4, lr = l & 15;
  const int sB = blockIdx.x * 128;
  const int s0 = sB + w * 32;       // this wave's 32-s strip
  __shared__ float RB[16][132];
  __shared__ int MK[2][132];
  __shared__ short SW[4][32][36];   // [wave][bh][s] eS tile
  __shared__ short pvT[4][64][36];  // [wave][dk][s] pos_v transposed

  // ---- hoisted global loads (pos_k 128B/lane + rab + mask + S-tile) ----
  float4 PK[2][2][2];
#pragma unroll
  for (int ni = 0; ni < 2; ++ni) {
    int s = s0 + ni * 16 + lr;
#pragma unroll
    for (int kk = 0; kk < 2; ++kk) {
      const float* pk = pos_k + ((size_t)t * 1024 + s) * 64 + kk * 32 + lg * 8;
      PK[ni][kk][0] = *(const float4*)pk;
      PK[ni][kk][1] = *(const float4*)(pk + 4);
    }
  }
  float4 rv[2];
  {
    int hr = tid >> 4, c0 = (tid & 15) * 4;
#pragma unroll
    for (int it = 0; it < 2; ++it)
      rv[it] = *(const float4*)(rab + ((size_t)hr * 1024 + t) * 1024 + sB + c0 + it * 64);
  }
  int4 mv = {1, 1, 1, 1};
  if (tid < 64) {
    int br = tid >> 5, c = (tid & 31) * 4;
    mv = *(const int4*)(mask + ((size_t)br * 1024 + t) * 1024 + sB + c);
  }
  // S tile (raw qk): per wave 32 bh x 32 s; lane: row l&31, col8 (l>>5)*8+rr*16
  {
    int row = l & 31, ch = l >> 5;
#pragma unroll
    for (int rr = 0; rr < 2; ++rr) {
      int c8 = ch * 8 + rr * 16;
      *(bf16x8*)&SW[w][row][c8] =
          *(const bf16x8*)(S + ((size_t)row * 1024 + t) * 1024 + s0 + c8);
    }
  }
  // stage rab/mask to LDS
  {
    int hr = tid >> 4, c0 = (tid & 15) * 4;
#pragma unroll
    for (int it = 0; it < 2; ++it) {
      int c = c0 + it * 64;
      RB[hr][c] = rv[it].x; RB[hr][c + 1] = rv[it].y;
      RB[hr][c + 2] = rv[it].z; RB[hr][c + 3] = rv[it].w;
    }
  }
  if (tid < 64) {
    int br = tid >> 5, c = (tid & 31) * 4;
    MK[br][c] = mv.x; MK[br][c + 1] = mv.y; MK[br][c + 2] = mv.z; MK[br][c + 3] = mv.w;
  }
  // ---- Bp MFMA (M=32 bh, N=32 s, K=64) from registers ----
  bf16x8 af[2][2];
#pragma unroll
  for (int mi = 0; mi < 2; ++mi)
#pragma unroll
    for (int kk = 0; kk < 2; ++kk) {
      int bh = mi * 16 + lr;
      af[mi][kk] = *(const bf16x8*)(q + ((size_t)bh * 1024 + t) * 64 + kk * 32 + lg * 8);
    }
  f32x4 acc[2][2] = {};
#pragma unroll
  for (int ni = 0; ni < 2; ++ni)
#pragma unroll
    for (int kk = 0; kk < 2; ++kk) {
      bf16x8 bfr;
      bfr[0] = f2b(PK[ni][kk][0].x); bfr[1] = f2b(PK[ni][kk][0].y);
      bfr[2] = f2b(PK[ni][kk][0].z); bfr[3] = f2b(PK[ni][kk][0].w);
      bfr[4] = f2b(PK[ni][kk][1].x); bfr[5] = f2b(PK[ni][kk][1].y);
      bfr[6] = f2b(PK[ni][kk][1].z); bfr[7] = f2b(PK[ni][kk][1].w);
#pragma unroll
      for (int mi = 0; mi < 2; ++mi) acc[mi][ni] = MFMA(af[mi][kk], bfr, acc[mi][ni]);
    }
  // ---- stage pos_v (PK registers now dead) into pvT[w][dk][s] ----
  {
    int sp = l & 15;  // s-row pair
#pragma unroll
    for (int c = 0; c < 4; ++c) {
      int dk4 = (l >> 4) * 4 + c * 16;
      const float* p0 = pos_v + ((size_t)t * 1024 + s0 + sp * 2) * 64 + dk4;
      float4 a = *(const float4*)p0;
      float4 b = *(const float4*)(p0 + 64);
      unsigned u0 = (unsigned)(unsigned short)f2b(a.x) | ((unsigned)(unsigned short)f2b(b.x) << 16);
      unsigned u1 = (unsigned)(unsigned short)f2b(a.y) | ((unsigned)(unsigned short)f2b(b.y) << 16);
      unsigned u2 = (unsigned)(unsigned short)f2b(a.z) | ((unsigned)(unsigned short)f2b(b.z) << 16);
      unsigned u3 = (unsigned)(unsigned short)f2b(a.w) | ((unsigned)(unsigned short)f2b(b.w) << 16);
      *(unsigned*)&pvT[w][dk4 + 0][sp * 2] = u0;
      *(unsigned*)&pvT[w][dk4 + 1][sp * 2] = u1;
      *(unsigned*)&pvT[w][dk4 + 2][sp * 2] = u2;
      *(unsigned*)&pvT[w][dk4 + 3][sp * 2] = u3;
    }
  }
  __syncthreads();  // RB/MK cross-wave visibility (SW/pvT per-wave)
  // ---- epilogue: exp(S + Bp + bias - 10), masked -> 0; overwrite SW ----
#pragma unroll
  for (int ni = 0; ni < 2; ++ni) {
    int col = ni * 16 + lr;
    int colw = w * 32 + col;
    int msk0 = MK[0][colw];
    int msk1 = MK[1][colw];
#pragma unroll
    for (int r = 0; r < 4; ++r) {
      int h = lg * 4 + r;
      float bv = RB[h][colw];
      float v0 = acc[0][ni][r] + bv + b2f(SW[w][h][col]);
      float v1 = acc[1][ni][r] + bv + b2f(SW[w][16 + h][col]);
      float e0 = (msk0 == 0) ? 0.f : __expf(v0 - 10.f);
      float e1 = (msk1 == 0) ? 0.f : __expf(v1 - 10.f);
      SW[w][h][col] = f2b(e0);
      SW[w][16 + h][col] = f2b(e1);
    }
  }
  // ---- pv MFMA: X0 += eS(32bh x 32s) @ pos_v(32s x 64dk) ----
  f32x4 apv[2][4] = {};
  {
    bf16x8 afr[2];
#pragma unroll
    for (int mi = 0; mi < 2; ++mi) {
      const short* sp = &SW[w][mi * 16 + lr][lg * 8];
      bf16x4 lo = *(const bf16x4*)sp;
      bf16x4 hi = *(const bf16x4*)(sp + 4);
      afr[mi][0] = lo[0]; afr[mi][1] = lo[1]; afr[mi][2] = lo[2]; afr[mi][3] = lo[3];
      afr[mi][4] = hi[0]; afr[mi][5] = hi[1]; afr[mi][6] = hi[2]; afr[mi][7] = hi[3];
    }
#pragma unroll
    for (int ni = 0; ni < 4; ++ni) {
      const short* pp = &pvT[w][ni * 16 + lr][lg * 8];
      bf16x4 lo = *(const bf16x4*)pp;
      bf16x4 hi = *(const bf16x4*)(pp + 4);
      bf16x8 bfr;
      bfr[0] = lo[0]; bfr[1] = lo[1]; bfr[2] = lo[2]; bfr[3] = lo[3];
      bfr[4] = hi[0]; bfr[5] = hi[1]; bfr[6] = hi[2]; bfr[7] = hi[3];
#pragma unroll
      for (int mi = 0; mi < 2; ++mi) apv[mi][ni] = MFMA(afr[mi], bfr, apv[mi][ni]);
    }
  }
  // write back eS
  {
    int row = l & 31, ch = l >> 5;
#pragma unroll
    for (int rr = 0; rr < 2; ++rr) {
      int c8 = ch * 8 + rr * 16;
      bf16x8 o = *(const bf16x8*)&SW[w][row][c8];
      *(bf16x8*)(S + ((size_t)row * 1024 + t) * 1024 + s0 + c8) = o;
    }
  }
  // atomic accumulate X0f (fp32; coalesced 16-lane dword segments)
#pragma unroll
  for (int mi = 0; mi < 2; ++mi)
#pragma unroll
    for (int ni = 0; ni < 4; ++ni)
#pragma unroll
      for (int r = 0; r < 4; ++r) {
        int bh2 = mi * 16 + lg * 4 + r;
        int b = bh2 >> 4, h = bh2 & 15;
        int dk = ni * 16 + lr;
        atomicAdd(&X0f[((size_t)(b * 1024 + t)) * 1024 + h * 64 + dk], apv[mi][ni][r]);
      }
}

// ---------------------------------------------------------------------------
// K4: X = bf16((X0f + eS @ v) / l), l = row-sum of eS computed inline.
__global__ __launch_bounds__(256) void k_av(
    const short* __restrict__ S, const short* __restrict__ vT,
    const float* __restrict__ X0f, short* __restrict__ X) {
  const int bh = blockIdx.y;
  const int tt0 = blockIdx.x * 32;
  const int tid = threadIdx.x;
  const int w = tid >> 6, l = tid & 63, lg = l >> 4, lr = l & 15;
  const int wm = w >> 1, wn = w & 1;
  const short* vbase = vT + ((size_t)bh << 16) + ((size_t)(wn * 32) << 10);
  const short* sbase = S + ((size_t)bh << 20) + ((size_t)(tt0 + wm * 16) << 10);
  f32x4 acc[2] = {};
  float lsum = 0.f;
#pragma unroll 8
  for (int kk = 0; kk < 32; ++kk) {
    bf16x8 afr = *(const bf16x8*)(sbase + ((size_t)lr << 10) + kk * 32 + lg * 8);
#pragma unroll
    for (int j = 0; j < 8; ++j) lsum += b2f(afr[j]);
#pragma unroll
    for (int ni = 0; ni < 2; ++ni) {
      bf16x8 bfr = *(const bf16x8*)(vbase + ((size_t)(ni * 16 + lr) << 10) + kk * 32 + lg * 8);
      acc[ni] = MFMA(afr, bfr, acc[ni]);
    }
  }
  lsum += __shfl_xor(lsum, 16);
  lsum += __shfl_xor(lsum, 32);
  const int b = bh >> 4, h = bh & 15;
#pragma unroll
  for (int ni = 0; ni < 2; ++ni)
#pragma unroll
    for (int r = 0; r < 4; ++r) {
      float lrow = __shfl(lsum, lg * 4 + r);
      float inv = 1.0f / lrow;
      int tt = tt0 + wm * 16 + lg * 4 + r;
      int d = h * 64 + wn * 32 + ni * 16 + lr;
      size_t idx = ((size_t)(b * 1024 + tt)) * 1024 + d;
      X[idx] = f2b((X0f[idx] + acc[ni][r]) * inv);
    }
}

// ---------------------------------------------------------------------------
// K5: out = X @ Wo + bo (fp32). 64x64 tile, BK=32, grid (16,32).
__global__ __launch_bounds__(256) void k_oproj(
    const short* __restrict__ X, const short* __restrict__ WT,
    const float* __restrict__ bias, float* __restrict__ out) {
  __shared__ short As[64 * 32];
  __shared__ short Bs[64 * 32];
  const int tid = threadIdx.x;
  const int w = tid >> 6, l = tid & 63, lg = l >> 4, lr = l & 15;
  const int wm = w >> 1, wn = w & 1;
  const int n0 = blockIdx.x * 64;
  const int m0 = blockIdx.y * 64;
  const short* Abase = X + ((size_t)m0 << 10);
  const short* Bbase = WT + ((size_t)n0 << 10);
  const int srow = l >> 2, scol8 = (l & 3) * 8;
  f32x4 acc[2][2] = {};
  for (int k0 = 0; k0 < 1024; k0 += 32) {
    gload16(Abase + (size_t)(w * 16 + srow) * 1024 + k0 + scol8, &As[w * 512]);
    gload16(Bbase + (size_t)(w * 16 + srow) * 1024 + k0 + scol8, &Bs[w * 512]);
    __syncthreads();
    bf16x8 af[2], bf[2];
#pragma unroll
    for (int i = 0; i < 2; ++i) af[i] = *(const bf16x8*)&As[(wm * 32 + i * 16 + lr) * 32 + lg * 8];
#pragma unroll
    for (int i = 0; i < 2; ++i) bf[i] = *(const bf16x8*)&Bs[(wn * 32 + i * 16 + lr) * 32 + lg * 8];
#pragma unroll
    for (int mi = 0; mi < 2; ++mi)
#pragma unroll
      for (int ni = 0; ni < 2; ++ni) acc[mi][ni] = MFMA(af[mi], bf[ni], acc[mi][ni]);
    __syncthreads();
  }
  float bvals[2];
#pragma unroll
  for (int ni = 0; ni < 2; ++ni) bvals[ni] = bias[n0 + wn * 32 + ni * 16 + lr];
#pragma unroll
  for (int mi = 0; mi < 2; ++mi)
#pragma unroll
    for (int ni = 0; ni < 2; ++ni)
#pragma unroll
      for (int r = 0; r < 4; ++r) {
        int m = m0 + wm * 32 + mi * 16 + lg * 4 + r;
        int n = n0 + wn * 32 + ni * 16 + lr;
        out[(size_t)m * 1024 + n] = acc[mi][ni][r] + bvals[ni];
      }
}

// ---------------------------------------------------------------------------
extern "C" void kernel_launch(void* const* d_in, const int* in_sizes, int n_in,
                              void* d_out, int out_size, void* d_ws, size_t ws_size,
                              hipStream_t stream) {
  (void)in_sizes; (void)n_in; (void)out_size; (void)ws_size;
  const float* query = (const float*)d_in[0];
  const float* key   = (const float*)d_in[1];
  const float* value = (const float*)d_in[2];
  const float* pos_k = (const float*)d_in[3];
  const float* pos_v = (const float*)d_in[4];
  const int*   mask  = (const int*)d_in[5];
  const float* rab   = (const float*)d_in[6];
  const float* Wq = (const float*)d_in[7];
  const float* bq = (const float*)d_in[8];
  const float* Wk = (const float*)d_in[9];
  const float* bk = (const float*)d_in[10];
  const float* Wv = (const float*)d_in[11];
  const float* bv = (const float*)d_in[12];
  const float* Wo = (const float*)d_in[13];
  const float* bo = (const float*)d_in[14];
  float* out = (float*)d_out;

  const size_t M2 = 2ull * 1024 * 1024;  // B*T*D elements
  short* q   = (short*)d_ws;
  short* k   = q + M2;
  short* vT  = k + M2;                    // [bh][dk][t]
  short* S   = vT + M2;                   // 32M bf16: raw scores then eS (in place)
  float* X0f = (float*)(S + 32ull * 1024 * 1024);  // 2M f32 (8 MB), atomic-accumulated
  short* X   = (short*)(X0f + M2);
  short* qin = X + M2;                    // stacked [3][2048][1024]
  short* kin = qin + M2;
  short* vin = kin + M2;
  short* WqT = vin + M2;                  // stacked [3+1][1024][1024]
  short* WkT = WqT + 1024 * 1024;
  short* WvT = WkT + 1024 * 1024;
  short* WoT = WvT + 1024 * 1024;

  hipMemsetAsync(X0f, 0, M2 * sizeof(float), stream);
  k_cvt3<<<dim3(1024, 3), dim3(256), 0, stream>>>(query, key, value, qin, kin, vin);
  k_wtrans4<<<dim3(16, 16, 4), dim3(256), 0, stream>>>(Wq, Wk, Wv, Wo, WqT, WkT, WvT, WoT);
  k_qkv<<<dim3(16, 48), dim3(256), 0, stream>>>(qin, WqT, bq, bk, bv, q, k, vT);
  k_qk<<<dim3(32, 32), dim3(512), 0, stream>>>(q, k, S);
  k_posk_pv<<<dim3(8, 1024), dim3(256), 0, stream>>>(q, pos_k, pos_v, rab, mask, S, X0f);
  k_av<<<dim3(32, 32), dim3(256), 0, stream>>>(S, vT, X0f, X);
  k_oproj<<<dim3(16, 32), dim3(256), 0, stream>>>(X, WoT, bo, out);
}

// Round 14
// 340.978 us; speedup vs baseline: 1.0945x; 1.0945x over previous
//
#include <hip/hip_runtime.h>

// MultiHeadedAttention with relative position (B=2, T=1024, D=1024, H=16, DK=64)
// Pipeline: cvt(inputs->bf16), wtrans(W->bf16 [n][k]) -> fused QKV GEMM (XCD-swizzled) ->
//   k_qk: S = q@k^T (raw, bf16) ->
//   k_posk_pv: per (half,t) block: S = exp(S + Bp + bias - 10) in place (masked->0)
//              AND X0p[half] = eS @ pos_v — wave partials reduced in LDS (XR overlay),
//              stored ONCE (no atomics) ->
//   X = (X0p0 + X0p1 + eS@v)/l (l inline) -> out = X@Wo+bo.
// softmax(s)@V == (exp(s-c)@V)/sum(exp(s-c)).

#define DEV __device__ __forceinline__

typedef short bf16x8 __attribute__((ext_vector_type(8)));
typedef short bf16x4 __attribute__((ext_vector_type(4)));
typedef float f32x4 __attribute__((ext_vector_type(4)));

DEV short f2b(float f) {
  unsigned u = __builtin_bit_cast(unsigned, f);
  u = (u + 0x7FFFu + ((u >> 16) & 1u)) >> 16;
  return (short)u;
}
DEV float b2f(short s) {
  unsigned u = ((unsigned)(unsigned short)s) << 16;
  return __builtin_bit_cast(float, u);
}

#define MFMA(a, b, c) __builtin_amdgcn_mfma_f32_16x16x32_bf16(a, b, c, 0, 0, 0)

DEV void gload16(const void* g, void* l) {
  __builtin_amdgcn_global_load_lds(
      (const __attribute__((address_space(1))) void*)g,
      (__attribute__((address_space(3))) void*)l, 16, 0, 0);
}

// ---------------------------------------------------------------------------
// P1: fp32 -> bf16 flat convert for query/key/value.
__global__ __launch_bounds__(256) void k_cvt3(
    const float* __restrict__ a, const float* __restrict__ b, const float* __restrict__ c,
    short* __restrict__ oa, short* __restrict__ ob, short* __restrict__ oc) {
  const float* src = blockIdx.y == 0 ? a : (blockIdx.y == 1 ? b : c);
  short* dst = blockIdx.y == 0 ? oa : (blockIdx.y == 1 ? ob : oc);
  size_t i = ((size_t)blockIdx.x * 256 + threadIdx.x) * 8;
  float4 p0 = *(const float4*)(src + i);
  float4 p1 = *(const float4*)(src + i + 4);
  bf16x8 o;
  o[0] = f2b(p0.x); o[1] = f2b(p0.y); o[2] = f2b(p0.z); o[3] = f2b(p0.w);
  o[4] = f2b(p1.x); o[5] = f2b(p1.y); o[6] = f2b(p1.z); o[7] = f2b(p1.w);
  *(bf16x8*)(dst + i) = o;
}

// P2: W [k][n] fp32 -> WT [n][k] bf16, 64x64 tiles via LDS.
__global__ __launch_bounds__(256) void k_wtrans4(
    const float* __restrict__ w0, const float* __restrict__ w1,
    const float* __restrict__ w2, const float* __restrict__ w3,
    short* __restrict__ o0, short* __restrict__ o1,
    short* __restrict__ o2, short* __restrict__ o3) {
  const float* src; short* dst;
  switch (blockIdx.z) {
    case 0: src = w0; dst = o0; break;
    case 1: src = w1; dst = o1; break;
    case 2: src = w2; dst = o2; break;
    default: src = w3; dst = o3;
  }
  __shared__ short LW[64][74];
  const int tid = threadIdx.x;
  const int k0 = blockIdx.y * 64, n0 = blockIdx.x * 64;
  {
    int c4 = (tid & 15) * 4;
#pragma unroll
    for (int i = 0; i < 4; ++i) {
      int r = (tid >> 4) + i * 16;
      float4 v = *(const float4*)(src + (size_t)(k0 + r) * 1024 + n0 + c4);
      LW[r][c4 + 0] = f2b(v.x); LW[r][c4 + 1] = f2b(v.y);
      LW[r][c4 + 2] = f2b(v.z); LW[r][c4 + 3] = f2b(v.w);
    }
  }
  __syncthreads();
  {
    int n = tid >> 2, kb = (tid & 3) * 16;
#pragma unroll
    for (int j2 = 0; j2 < 2; ++j2) {
      int kk = kb + j2 * 8;
      bf16x8 o;
#pragma unroll
      for (int j = 0; j < 8; ++j) o[j] = LW[kk + j][n];
      *(bf16x8*)(dst + (size_t)(n0 + n) * 1024 + k0 + kk) = o;
    }
  }
}

// ---------------------------------------------------------------------------
// K1: fused QKV projection with bijective XCD chunk-swizzle.
__global__ __launch_bounds__(256) void k_qkv(
    const short* __restrict__ Ain, const short* __restrict__ WT,
    const float* __restrict__ bq, const float* __restrict__ bk,
    const float* __restrict__ bv,
    short* __restrict__ qo, short* __restrict__ ko, short* __restrict__ vTo) {
  __shared__ short As[128 * 32];
  __shared__ short Bs[64 * 32];
  __shared__ short LW[128][72];
  const int tid = threadIdx.x;
  const int w = tid >> 6, l = tid & 63, lg = l >> 4, lr = l & 15;
  const int wm = w >> 1, wn = w & 1;
  const int flat = blockIdx.x + gridDim.x * blockIdx.y;  // 0..767
  const int flat2 = (flat & 7) * 96 + (flat >> 3);
  const int n0 = (flat2 & 15) * 64;
  const int m0 = (flat2 >> 4) * 128;
  const int seg = m0 >> 11;
  const int mseg = m0 & 2047;
  const short* Abase = Ain + ((size_t)m0 << 10);
  const short* Bbase = WT + ((size_t)seg << 20) + ((size_t)n0 << 10);
  const int srow = l >> 2, scol8 = (l & 3) * 8;
  f32x4 acc[4][2] = {};
  for (int k0 = 0; k0 < 1024; k0 += 32) {
    gload16(Abase + (size_t)((w * 2) * 16 + srow) * 1024 + k0 + scol8, &As[(w * 2) * 512]);
    gload16(Abase + (size_t)((w * 2 + 1) * 16 + srow) * 1024 + k0 + scol8, &As[(w * 2 + 1) * 512]);
    gload16(Bbase + (size_t)(w * 16 + srow) * 1024 + k0 + scol8, &Bs[w * 512]);
    __syncthreads();
    bf16x8 af[4], bf[2];
#pragma unroll
    for (int i = 0; i < 4; ++i) af[i] = *(const bf16x8*)&As[(wm * 64 + i * 16 + lr) * 32 + lg * 8];
#pragma unroll
    for (int i = 0; i < 2; ++i) bf[i] = *(const bf16x8*)&Bs[(wn * 32 + i * 16 + lr) * 32 + lg * 8];
#pragma unroll
    for (int mi = 0; mi < 4; ++mi)
#pragma unroll
      for (int ni = 0; ni < 2; ++ni) acc[mi][ni] = MFMA(af[mi], bf[ni], acc[mi][ni]);
    __syncthreads();
  }
  const float* bias = seg == 0 ? bq : (seg == 1 ? bk : bv);
  const float scale = seg == 0 ? 0.125f : 1.0f;
  float bvals[2];
#pragma unroll
  for (int ni = 0; ni < 2; ++ni) bvals[ni] = bias[n0 + wn * 32 + ni * 16 + lr];
#pragma unroll
  for (int mi = 0; mi < 4; ++mi)
#pragma unroll
    for (int ni = 0; ni < 2; ++ni)
#pragma unroll
      for (int r = 0; r < 4; ++r)
        LW[wm * 64 + mi * 16 + lg * 4 + r][wn * 32 + ni * 16 + lr] =
            f2b((acc[mi][ni][r] + bvals[ni]) * scale);
  __syncthreads();
  if (seg < 2) {
    short* dst = seg == 0 ? qo : ko;
    int r = tid >> 1, half = tid & 1;
    int m = mseg + r, b = m >> 10, t = m & 1023;
    int h = n0 >> 6;
#pragma unroll
    for (int g = 0; g < 4; ++g) {
      int dk = half * 32 + g * 8;
      bf16x8 o = *(const bf16x8*)&LW[r][dk];
      *(bf16x8*)(dst + (((size_t)(b * 16 + h) * 1024 + t) << 6) + dk) = o;
    }
  } else {
    int dkc = tid & 63, th = tid >> 6;
    int h = n0 >> 6, dk = dkc;
    int b = mseg >> 10;
    int tbase = (mseg & 1023) + th * 32;
#pragma unroll
    for (int g = 0; g < 4; ++g) {
      bf16x8 o;
#pragma unroll
      for (int e = 0; e < 8; ++e) o[e] = LW[th * 32 + g * 8 + e][dkc];
      *(bf16x8*)(vTo + (((size_t)(b * 16 + h) * 64 + dk) << 10) + tbase + g * 8) = o;
    }
  }
}

// ---------------------------------------------------------------------------
// K2a: S = q@k^T raw scores (bf16). grid (T/32, bh); 8 waves, wave 16t x 256s.
__global__ __launch_bounds__(512, 2) void k_qk(
    const short* __restrict__ q, const short* __restrict__ kmat,
    short* __restrict__ S) {
  const int bh = blockIdx.y;
  const int tid = threadIdx.x;
  const int w = tid >> 6, l = tid & 63, lg = l >> 4, lr = l & 15;
  const int wm = w >> 2, wn = w & 3;
  const int t0 = blockIdx.x * 32 + wm * 16;
  const int scol = wn * 256;
  __shared__ short LS[8][16][266];

  bf16x8 af[2];
#pragma unroll
  for (int kk = 0; kk < 2; ++kk)
    af[kk] = *(const bf16x8*)(q + ((size_t)bh * 1024 + (t0 + lr)) * 64 + kk * 32 + lg * 8);

#pragma unroll
  for (int ni = 0; ni < 16; ++ni) {
    int s = scol + ni * 16 + lr;
    const short* kp = kmat + ((size_t)bh * 1024 + s) * 64 + lg * 8;
    f32x4 a = {};
    a = MFMA(af[0], *(const bf16x8*)kp, a);
    a = MFMA(af[1], *(const bf16x8*)(kp + 32), a);
#pragma unroll
    for (int r = 0; r < 4; ++r) LS[w][lg * 4 + r][ni * 16 + lr] = f2b(a[r]);
  }
  short* sb = S + ((size_t)bh * 1024 + t0) * 1024 + scol;
  const int r2 = l >> 5, c16 = (l & 31) * 8;
#pragma unroll
  for (int rr = 0; rr < 8; ++rr) {
    int row = rr * 2 + r2;
    bf16x8 o = *(const bf16x8*)&LS[w][row][c16];
    *(bf16x8*)(sb + (size_t)row * 1024 + c16) = o;
  }
}

// ---------------------------------------------------------------------------
// K2b+K3 merged, NO atomics. grid (2 halves, t); 4 waves.
// Per round (4 rounds x 32 s per wave): S = exp(S + q.pos_k + bias - 10)
// (masked->0) in place; apv += eS @ pos_v (registers). After the loop the 4
// wave partials are reduced through an LDS overlay (XR) and stored ONCE.
__global__ __launch_bounds__(256) void k_posk_pv(
    const short* __restrict__ q, const float* __restrict__ pos_k,
    const float* __restrict__ pos_v, const float* __restrict__ rab,
    const int* __restrict__ mask, short* __restrict__ S,
    float* __restrict__ X0p) {
  const int half = blockIdx.x;
  const int t = blockIdx.y;
  const int tid = threadIdx.x;
  const int w = tid >> 6, l = tid & 63, lg = l >> 4, lr = l & 15;
  // SW[4][32][36] (9216 B) + pvT[4][64][36] (18432 B) = 27648 B during the loop;
  // XR[4][32][64] f32 (32768 B) overlays both after the loop (barrier-guarded).
  __shared__ __align__(16) char smem_raw[32768];
  auto SW  = (short (*)[32][36])smem_raw;
  auto pvT = (short (*)[64][36])(smem_raw + 9216);
  auto XR  = (float (*)[32][64])smem_raw;

  // q A-frags (reused all rounds)
  bf16x8 af[2][2];
#pragma unroll
  for (int mi = 0; mi < 2; ++mi)
#pragma unroll
    for (int kk = 0; kk < 2; ++kk)
      af[mi][kk] = *(const bf16x8*)(q + ((size_t)(mi * 16 + lr) * 1024 + t) * 64 + kk * 32 + lg * 8);

  f32x4 apv[2][4] = {};

  for (int rnd = 0; rnd < 4; ++rnd) {
    const int s0 = half * 512 + rnd * 128 + w * 32;
    // ---- hoisted global loads ----
    float4 PK[2][2][2];
#pragma unroll
    for (int ni = 0; ni < 2; ++ni) {
      int s = s0 + ni * 16 + lr;
#pragma unroll
      for (int kk = 0; kk < 2; ++kk) {
        const float* pk = pos_k + ((size_t)t * 1024 + s) * 64 + kk * 32 + lg * 8;
        PK[ni][kk][0] = *(const float4*)pk;
        PK[ni][kk][1] = *(const float4*)(pk + 4);
      }
    }
    float rv[2][4];
    int msk[2][2];
#pragma unroll
    for (int ni = 0; ni < 2; ++ni) {
      int s = s0 + ni * 16 + lr;
#pragma unroll
      for (int r = 0; r < 4; ++r)
        rv[ni][r] = rab[((size_t)(lg * 4 + r) * 1024 + t) * 1024 + s];
      msk[0][ni] = mask[(size_t)t * 1024 + s];
      msk[1][ni] = mask[(size_t)(1024 + t) * 1024 + s];
    }
    // ---- S tile -> SW (per-wave, vector) ----
    {
      int row = l & 31, ch = l >> 5;
#pragma unroll
      for (int rr = 0; rr < 2; ++rr) {
        int c8 = ch * 8 + rr * 16;
        *(bf16x8*)&SW[w][row][c8] =
            *(const bf16x8*)(S + ((size_t)row * 1024 + t) * 1024 + s0 + c8);
      }
    }
    // ---- pos_v -> pvT[w][dk][s32] ----
    {
      int sp = l & 15;
#pragma unroll
      for (int c = 0; c < 4; ++c) {
        int dk4 = (l >> 4) * 4 + c * 16;
        const float* p0 = pos_v + ((size_t)t * 1024 + s0 + sp * 2) * 64 + dk4;
        float4 a = *(const float4*)p0;
        float4 b = *(const float4*)(p0 + 64);
        unsigned u0 = (unsigned)(unsigned short)f2b(a.x) | ((unsigned)(unsigned short)f2b(b.x) << 16);
        unsigned u1 = (unsigned)(unsigned short)f2b(a.y) | ((unsigned)(unsigned short)f2b(b.y) << 16);
        unsigned u2 = (unsigned)(unsigned short)f2b(a.z) | ((unsigned)(unsigned short)f2b(b.z) << 16);
        unsigned u3 = (unsigned)(unsigned short)f2b(a.w) | ((unsigned)(unsigned short)f2b(b.w) << 16);
        *(unsigned*)&pvT[w][dk4 + 0][sp * 2] = u0;
        *(unsigned*)&pvT[w][dk4 + 1][sp * 2] = u1;
        *(unsigned*)&pvT[w][dk4 + 2][sp * 2] = u2;
        *(unsigned*)&pvT[w][dk4 + 3][sp * 2] = u3;
      }
    }
    // ---- Bp MFMA (M=32 bh, N=32 s, K=64) from registers ----
    f32x4 acc[2][2] = {};
#pragma unroll
    for (int ni = 0; ni < 2; ++ni)
#pragma unroll
      for (int kk = 0; kk < 2; ++kk) {
        bf16x8 bfr;
        bfr[0] = f2b(PK[ni][kk][0].x); bfr[1] = f2b(PK[ni][kk][0].y);
        bfr[2] = f2b(PK[ni][kk][0].z); bfr[3] = f2b(PK[ni][kk][0].w);
        bfr[4] = f2b(PK[ni][kk][1].x); bfr[5] = f2b(PK[ni][kk][1].y);
        bfr[6] = f2b(PK[ni][kk][1].z); bfr[7] = f2b(PK[ni][kk][1].w);
#pragma unroll
        for (int mi = 0; mi < 2; ++mi) acc[mi][ni] = MFMA(af[mi][kk], bfr, acc[mi][ni]);
      }
    // ---- epilogue: exp(S + Bp + bias - 10), masked -> 0; overwrite SW ----
#pragma unroll
    for (int ni = 0; ni < 2; ++ni) {
      int col = ni * 16 + lr;
#pragma unroll
      for (int r = 0; r < 4; ++r) {
        int h = lg * 4 + r;
        float v0 = acc[0][ni][r] + rv[ni][r] + b2f(SW[w][h][col]);
        float v1 = acc[1][ni][r] + rv[ni][r] + b2f(SW[w][16 + h][col]);
        float e0 = (msk[0][ni] == 0) ? 0.f : __expf(v0 - 10.f);
        float e1 = (msk[1][ni] == 0) ? 0.f : __expf(v1 - 10.f);
        SW[w][h][col] = f2b(e0);
        SW[w][16 + h][col] = f2b(e1);
      }
    }
    // ---- write back eS (per-wave tile, vector) ----
    {
      int row = l & 31, ch = l >> 5;
#pragma unroll
      for (int rr = 0; rr < 2; ++rr) {
        int c8 = ch * 8 + rr * 16;
        bf16x8 o = *(const bf16x8*)&SW[w][row][c8];
        *(bf16x8*)(S + ((size_t)row * 1024 + t) * 1024 + s0 + c8) = o;
      }
    }
    // ---- pv MFMA: apv += eS(32bh x 32s) @ pos_v(32s x 64dk) ----
    {
      bf16x8 afr[2];
#pragma unroll
      for (int mi = 0; mi < 2; ++mi) {
        const short* sp2 = &SW[w][mi * 16 + lr][lg * 8];
        bf16x4 lo = *(const bf16x4*)sp2;
        bf16x4 hi = *(const bf16x4*)(sp2 + 4);
        afr[mi][0] = lo[0]; afr[mi][1] = lo[1]; afr[mi][2] = lo[2]; afr[mi][3] = lo[3];
        afr[mi][4] = hi[0]; afr[mi][5] = hi[1]; afr[mi][6] = hi[2]; afr[mi][7] = hi[3];
      }
#pragma unroll
      for (int ni = 0; ni < 4; ++ni) {
        const short* pp = &pvT[w][ni * 16 + lr][lg * 8];
        bf16x4 lo = *(const bf16x4*)pp;
        bf16x4 hi = *(const bf16x4*)(pp + 4);
        bf16x8 bfr;
        bfr[0] = lo[0]; bfr[1] = lo[1]; bfr[2] = lo[2]; bfr[3] = lo[3];
        bfr[4] = hi[0]; bfr[5] = hi[1]; bfr[6] = hi[2]; bfr[7] = hi[3];
#pragma unroll
        for (int mi = 0; mi < 2; ++mi) apv[mi][ni] = MFMA(afr[mi], bfr, apv[mi][ni]);
      }
    }
  }
  // ---- cross-wave reduction of apv partials (the R13 bug fix) ----
  __syncthreads();  // SW/pvT dead; reuse storage as XR
#pragma unroll
  for (int mi = 0; mi < 2; ++mi)
#pragma unroll
    for (int ni = 0; ni < 4; ++ni)
#pragma unroll
      for (int r = 0; r < 4; ++r)
        XR[w][mi * 16 + lg * 4 + r][ni * 16 + lr] = apv[mi][ni][r];
  __syncthreads();
  {
    int bh2 = tid >> 3;        // 0..31
    int dk0 = (tid & 7) * 8;   // 0,8,..56
    int b = bh2 >> 4, h = bh2 & 15;
    float4 a0 = *(const float4*)&XR[0][bh2][dk0];
    float4 a1 = *(const float4*)&XR[1][bh2][dk0];
    float4 a2 = *(const float4*)&XR[2][bh2][dk0];
    float4 a3 = *(const float4*)&XR[3][bh2][dk0];
    float4 b0 = *(const float4*)&XR[0][bh2][dk0 + 4];
    float4 b1 = *(const float4*)&XR[1][bh2][dk0 + 4];
    float4 b2 = *(const float4*)&XR[2][bh2][dk0 + 4];
    float4 b3 = *(const float4*)&XR[3][bh2][dk0 + 4];
    float4 s0v, s1v;
    s0v.x = a0.x + a1.x + a2.x + a3.x; s0v.y = a0.y + a1.y + a2.y + a3.y;
    s0v.z = a0.z + a1.z + a2.z + a3.z; s0v.w = a0.w + a1.w + a2.w + a3.w;
    s1v.x = b0.x + b1.x + b2.x + b3.x; s1v.y = b0.y + b1.y + b2.y + b3.y;
    s1v.z = b0.z + b1.z + b2.z + b3.z; s1v.w = b0.w + b1.w + b2.w + b3.w;
    float* dst = X0p + ((size_t)half << 21) + ((size_t)(b * 1024 + t)) * 1024 + h * 64 + dk0;
    *(float4*)dst = s0v;
    *(float4*)(dst + 4) = s1v;
  }
}

// ---------------------------------------------------------------------------
// K4: X = bf16((X0p0 + X0p1 + eS @ v) / l), l = row-sum of eS computed inline.
__global__ __launch_bounds__(256) void k_av(
    const short* __restrict__ S, const short* __restrict__ vT,
    const float* __restrict__ X0p, short* __restrict__ X) {
  const int bh = blockIdx.y;
  const int tt0 = blockIdx.x * 32;
  const int tid = threadIdx.x;
  const int w = tid >> 6, l = tid & 63, lg = l >> 4, lr = l & 15;
  const int wm = w >> 1, wn = w & 1;
  const short* vbase = vT + ((size_t)bh << 16) + ((size_t)(wn * 32) << 10);
  const short* sbase = S + ((size_t)bh << 20) + ((size_t)(tt0 + wm * 16) << 10);
  f32x4 acc[2] = {};
  float lsum = 0.f;
#pragma unroll 8
  for (int kk = 0; kk < 32; ++kk) {
    bf16x8 afr = *(const bf16x8*)(sbase + ((size_t)lr << 10) + kk * 32 + lg * 8);
#pragma unroll
    for (int j = 0; j < 8; ++j) lsum += b2f(afr[j]);
#pragma unroll
    for (int ni = 0; ni < 2; ++ni) {
      bf16x8 bfr = *(const bf16x8*)(vbase + ((size_t)(ni * 16 + lr) << 10) + kk * 32 + lg * 8);
      acc[ni] = MFMA(afr, bfr, acc[ni]);
    }
  }
  lsum += __shfl_xor(lsum, 16);
  lsum += __shfl_xor(lsum, 32);
  const int b = bh >> 4, h = bh & 15;
#pragma unroll
  for (int ni = 0; ni < 2; ++ni)
#pragma unroll
    for (int r = 0; r < 4; ++r) {
      float lrow = __shfl(lsum, lg * 4 + r);
      float inv = 1.0f / lrow;
      int tt = tt0 + wm * 16 + lg * 4 + r;
      int d = h * 64 + wn * 32 + ni * 16 + lr;
      size_t idx = ((size_t)(b * 1024 + tt)) * 1024 + d;
      X[idx] = f2b((X0p[idx] + X0p[idx + (1u << 21)] + acc[ni][r]) * inv);
    }
}

// ---------------------------------------------------------------------------
// K5: out = X @ Wo + bo (fp32). 64x64 tile, BK=32, grid (16,32).
__global__ __launch_bounds__(256) void k_oproj(
    const short* __restrict__ X, const short* __restrict__ WT,
    const float* __restrict__ bias, float* __restrict__ out) {
  __shared__ short As[64 * 32];
  __shared__ short Bs[64 * 32];
  const int tid = threadIdx.x;
  const int w = tid >> 6, l = tid & 63, lg = l >> 4, lr = l & 15;
  const int wm = w >> 1, wn = w & 1;
  const int n0 = blockIdx.x * 64;
  const int m0 = blockIdx.y * 64;
  const short* Abase = X + ((size_t)m0 << 10);
  const short* Bbase = WT + ((size_t)n0 << 10);
  const int srow = l >> 2, scol8 = (l & 3) * 8;
  f32x4 acc[2][2] = {};
  for (int k0 = 0; k0 < 1024; k0 += 32) {
    gload16(Abase + (size_t)(w * 16 + srow) * 1024 + k0 + scol8, &As[w * 512]);
    gload16(Bbase + (size_t)(w * 16 + srow) * 1024 + k0 + scol8, &Bs[w * 512]);
    __syncthreads();
    bf16x8 af[2], bf[2];
#pragma unroll
    for (int i = 0; i < 2; ++i) af[i] = *(const bf16x8*)&As[(wm * 32 + i * 16 + lr) * 32 + lg * 8];
#pragma unroll
    for (int i = 0; i < 2; ++i) bf[i] = *(const bf16x8*)&Bs[(wn * 32 + i * 16 + lr) * 32 + lg * 8];
#pragma unroll
    for (int mi = 0; mi < 2; ++mi)
#pragma unroll
      for (int ni = 0; ni < 2; ++ni) acc[mi][ni] = MFMA(af[mi], bf[ni], acc[mi][ni]);
    __syncthreads();
  }
  float bvals[2];
#pragma unroll
  for (int ni = 0; ni < 2; ++ni) bvals[ni] = bias[n0 + wn * 32 + ni * 16 + lr];
#pragma unroll
  for (int mi = 0; mi < 2; ++mi)
#pragma unroll
    for (int ni = 0; ni < 2; ++ni)
#pragma unroll
      for (int r = 0; r < 4; ++r) {
        int m = m0 + wm * 32 + mi * 16 + lg * 4 + r;
        int n = n0 + wn * 32 + ni * 16 + lr;
        out[(size_t)m * 1024 + n] = acc[mi][ni][r] + bvals[ni];
      }
}

// ---------------------------------------------------------------------------
extern "C" void kernel_launch(void* const* d_in, const int* in_sizes, int n_in,
                              void* d_out, int out_size, void* d_ws, size_t ws_size,
                              hipStream_t stream) {
  (void)in_sizes; (void)n_in; (void)out_size; (void)ws_size;
  const float* query = (const float*)d_in[0];
  const float* key   = (const float*)d_in[1];
  const float* value = (const float*)d_in[2];
  const float* pos_k = (const float*)d_in[3];
  const float* pos_v = (const float*)d_in[4];
  const int*   mask  = (const int*)d_in[5];
  const float* rab   = (const float*)d_in[6];
  const float* Wq = (const float*)d_in[7];
  const float* bq = (const float*)d_in[8];
  const float* Wk = (const float*)d_in[9];
  const float* bk = (const float*)d_in[10];
  const float* Wv = (const float*)d_in[11];
  const float* bv = (const float*)d_in[12];
  const float* Wo = (const float*)d_in[13];
  const float* bo = (const float*)d_in[14];
  float* out = (float*)d_out;

  const size_t M2 = 2ull * 1024 * 1024;  // B*T*D elements
  short* q   = (short*)d_ws;
  short* k   = q + M2;
  short* vT  = k + M2;                    // [bh][dk][t]
  short* S   = vT + M2;                   // 32M bf16: raw scores then eS (in place)
  float* X0p = (float*)(S + 32ull * 1024 * 1024);  // 2 halves x 2M f32 (16 MB)
  short* X   = (short*)(X0p + 2 * M2);
  short* qin = X + M2;                    // stacked [3][2048][1024]
  short* kin = qin + M2;
  short* vin = kin + M2;
  short* WqT = vin + M2;                  // stacked [3+1][1024][1024]
  short* WkT = WqT + 1024 * 1024;
  short* WvT = WkT + 1024 * 1024;
  short* WoT = WvT + 1024 * 1024;

  k_cvt3<<<dim3(1024, 3), dim3(256), 0, stream>>>(query, key, value, qin, kin, vin);
  k_wtrans4<<<dim3(16, 16, 4), dim3(256), 0, stream>>>(Wq, Wk, Wv, Wo, WqT, WkT, WvT, WoT);
  k_qkv<<<dim3(16, 48), dim3(256), 0, stream>>>(qin, WqT, bq, bk, bv, q, k, vT);
  k_qk<<<dim3(32, 32), dim3(512), 0, stream>>>(q, k, S);
  k_posk_pv<<<dim3(2, 1024), dim3(256), 0, stream>>>(q, pos_k, pos_v, rab, mask, S, X0p);
  k_av<<<dim3(32, 32), dim3(256), 0, stream>>>(S, vT, X0p, X);
  k_oproj<<<dim3(16, 32), dim3(256), 0, stream>>>(X, WoT, bo, out);
}

// Round 15
// 314.724 us; speedup vs baseline: 1.1858x; 1.0834x over previous
//
#include <hip/hip_runtime.h>

// MultiHeadedAttention with relative position (B=2, T=1024, D=1024, H=16, DK=64)
// Pipeline (R11 structure, higher-concurrency streamers):
//   cvt(inputs->bf16), wtrans(W->bf16 [n][k]) -> fused QKV GEMM (XCD-swizzled) ->
//   k_qk: S = q@k^T (raw, bf16) -> k_posk_exp: S = exp(S + Bp + bias - 10) in place
//   (masked->0; grid (8,1024), 8 blocks/CU) ->
//   X0p[4] = eS@pos_v quarters (double-buffered LDS, issue-early/write-late) ->
//   X = (sum X0p + eS@v)/l (l inline) -> out = X@Wo+bo.
// softmax(s)@V == (exp(s-c)@V)/sum(exp(s-c)).

#define DEV __device__ __forceinline__

typedef short bf16x8 __attribute__((ext_vector_type(8)));
typedef short bf16x4 __attribute__((ext_vector_type(4)));
typedef float f32x4 __attribute__((ext_vector_type(4)));

DEV short f2b(float f) {
  unsigned u = __builtin_bit_cast(unsigned, f);
  u = (u + 0x7FFFu + ((u >> 16) & 1u)) >> 16;
  return (short)u;
}
DEV float b2f(short s) {
  unsigned u = ((unsigned)(unsigned short)s) << 16;
  return __builtin_bit_cast(float, u);
}

#define MFMA(a, b, c) __builtin_amdgcn_mfma_f32_16x16x32_bf16(a, b, c, 0, 0, 0)

DEV void gload16(const void* g, void* l) {
  __builtin_amdgcn_global_load_lds(
      (const __attribute__((address_space(1))) void*)g,
      (__attribute__((address_space(3))) void*)l, 16, 0, 0);
}

// ---------------------------------------------------------------------------
// P1: fp32 -> bf16 flat convert for query/key/value.
__global__ __launch_bounds__(256) void k_cvt3(
    const float* __restrict__ a, const float* __restrict__ b, const float* __restrict__ c,
    short* __restrict__ oa, short* __restrict__ ob, short* __restrict__ oc) {
  const float* src = blockIdx.y == 0 ? a : (blockIdx.y == 1 ? b : c);
  short* dst = blockIdx.y == 0 ? oa : (blockIdx.y == 1 ? ob : oc);
  size_t i = ((size_t)blockIdx.x * 256 + threadIdx.x) * 8;
  float4 p0 = *(const float4*)(src + i);
  float4 p1 = *(const float4*)(src + i + 4);
  bf16x8 o;
  o[0] = f2b(p0.x); o[1] = f2b(p0.y); o[2] = f2b(p0.z); o[3] = f2b(p0.w);
  o[4] = f2b(p1.x); o[5] = f2b(p1.y); o[6] = f2b(p1.z); o[7] = f2b(p1.w);
  *(bf16x8*)(dst + i) = o;
}

// P2: W [k][n] fp32 -> WT [n][k] bf16, 64x64 tiles via LDS.
__global__ __launch_bounds__(256) void k_wtrans4(
    const float* __restrict__ w0, const float* __restrict__ w1,
    const float* __restrict__ w2, const float* __restrict__ w3,
    short* __restrict__ o0, short* __restrict__ o1,
    short* __restrict__ o2, short* __restrict__ o3) {
  const float* src; short* dst;
  switch (blockIdx.z) {
    case 0: src = w0; dst = o0; break;
    case 1: src = w1; dst = o1; break;
    case 2: src = w2; dst = o2; break;
    default: src = w3; dst = o3;
  }
  __shared__ short LW[64][74];
  const int tid = threadIdx.x;
  const int k0 = blockIdx.y * 64, n0 = blockIdx.x * 64;
  {
    int c4 = (tid & 15) * 4;
#pragma unroll
    for (int i = 0; i < 4; ++i) {
      int r = (tid >> 4) + i * 16;
      float4 v = *(const float4*)(src + (size_t)(k0 + r) * 1024 + n0 + c4);
      LW[r][c4 + 0] = f2b(v.x); LW[r][c4 + 1] = f2b(v.y);
      LW[r][c4 + 2] = f2b(v.z); LW[r][c4 + 3] = f2b(v.w);
    }
  }
  __syncthreads();
  {
    int n = tid >> 2, kb = (tid & 3) * 16;
#pragma unroll
    for (int j2 = 0; j2 < 2; ++j2) {
      int kk = kb + j2 * 8;
      bf16x8 o;
#pragma unroll
      for (int j = 0; j < 8; ++j) o[j] = LW[kk + j][n];
      *(bf16x8*)(dst + (size_t)(n0 + n) * 1024 + k0 + kk) = o;
    }
  }
}

// ---------------------------------------------------------------------------
// K1: fused QKV projection with bijective XCD chunk-swizzle.
__global__ __launch_bounds__(256) void k_qkv(
    const short* __restrict__ Ain, const short* __restrict__ WT,
    const float* __restrict__ bq, const float* __restrict__ bk,
    const float* __restrict__ bv,
    short* __restrict__ qo, short* __restrict__ ko, short* __restrict__ vTo) {
  __shared__ short As[128 * 32];
  __shared__ short Bs[64 * 32];
  __shared__ short LW[128][72];
  const int tid = threadIdx.x;
  const int w = tid >> 6, l = tid & 63, lg = l >> 4, lr = l & 15;
  const int wm = w >> 1, wn = w & 1;
  const int flat = blockIdx.x + gridDim.x * blockIdx.y;  // 0..767
  const int flat2 = (flat & 7) * 96 + (flat >> 3);
  const int n0 = (flat2 & 15) * 64;
  const int m0 = (flat2 >> 4) * 128;
  const int seg = m0 >> 11;
  const int mseg = m0 & 2047;
  const short* Abase = Ain + ((size_t)m0 << 10);
  const short* Bbase = WT + ((size_t)seg << 20) + ((size_t)n0 << 10);
  const int srow = l >> 2, scol8 = (l & 3) * 8;
  f32x4 acc[4][2] = {};
  for (int k0 = 0; k0 < 1024; k0 += 32) {
    gload16(Abase + (size_t)((w * 2) * 16 + srow) * 1024 + k0 + scol8, &As[(w * 2) * 512]);
    gload16(Abase + (size_t)((w * 2 + 1) * 16 + srow) * 1024 + k0 + scol8, &As[(w * 2 + 1) * 512]);
    gload16(Bbase + (size_t)(w * 16 + srow) * 1024 + k0 + scol8, &Bs[w * 512]);
    __syncthreads();
    bf16x8 af[4], bf[2];
#pragma unroll
    for (int i = 0; i < 4; ++i) af[i] = *(const bf16x8*)&As[(wm * 64 + i * 16 + lr) * 32 + lg * 8];
#pragma unroll
    for (int i = 0; i < 2; ++i) bf[i] = *(const bf16x8*)&Bs[(wn * 32 + i * 16 + lr) * 32 + lg * 8];
#pragma unroll
    for (int mi = 0; mi < 4; ++mi)
#pragma unroll
      for (int ni = 0; ni < 2; ++ni) acc[mi][ni] = MFMA(af[mi], bf[ni], acc[mi][ni]);
    __syncthreads();
  }
  const float* bias = seg == 0 ? bq : (seg == 1 ? bk : bv);
  const float scale = seg == 0 ? 0.125f : 1.0f;
  float bvals[2];
#pragma unroll
  for (int ni = 0; ni < 2; ++ni) bvals[ni] = bias[n0 + wn * 32 + ni * 16 + lr];
#pragma unroll
  for (int mi = 0; mi < 4; ++mi)
#pragma unroll
    for (int ni = 0; ni < 2; ++ni)
#pragma unroll
      for (int r = 0; r < 4; ++r)
        LW[wm * 64 + mi * 16 + lg * 4 + r][wn * 32 + ni * 16 + lr] =
            f2b((acc[mi][ni][r] + bvals[ni]) * scale);
  __syncthreads();
  if (seg < 2) {
    short* dst = seg == 0 ? qo : ko;
    int r = tid >> 1, half = tid & 1;
    int m = mseg + r, b = m >> 10, t = m & 1023;
    int h = n0 >> 6;
#pragma unroll
    for (int g = 0; g < 4; ++g) {
      int dk = half * 32 + g * 8;
      bf16x8 o = *(const bf16x8*)&LW[r][dk];
      *(bf16x8*)(dst + (((size_t)(b * 16 + h) * 1024 + t) << 6) + dk) = o;
    }
  } else {
    int dkc = tid & 63, th = tid >> 6;
    int h = n0 >> 6, dk = dkc;
    int b = mseg >> 10;
    int tbase = (mseg & 1023) + th * 32;
#pragma unroll
    for (int g = 0; g < 4; ++g) {
      bf16x8 o;
#pragma unroll
      for (int e = 0; e < 8; ++e) o[e] = LW[th * 32 + g * 8 + e][dkc];
      *(bf16x8*)(vTo + (((size_t)(b * 16 + h) * 64 + dk) << 10) + tbase + g * 8) = o;
    }
  }
}

// ---------------------------------------------------------------------------
// K2a: S = q@k^T raw scores (bf16). grid (T/32, bh); 8 waves, wave 16t x 256s.
__global__ __launch_bounds__(512, 2) void k_qk(
    const short* __restrict__ q, const short* __restrict__ kmat,
    short* __restrict__ S) {
  const int bh = blockIdx.y;
  const int tid = threadIdx.x;
  const int w = tid >> 6, l = tid & 63, lg = l >> 4, lr = l & 15;
  const int wm = w >> 2, wn = w & 3;
  const int t0 = blockIdx.x * 32 + wm * 16;
  const int scol = wn * 256;
  __shared__ short LS[8][16][266];

  bf16x8 af[2];
#pragma unroll
  for (int kk = 0; kk < 2; ++kk)
    af[kk] = *(const bf16x8*)(q + ((size_t)bh * 1024 + (t0 + lr)) * 64 + kk * 32 + lg * 8);

#pragma unroll
  for (int ni = 0; ni < 16; ++ni) {
    int s = scol + ni * 16 + lr;
    const short* kp = kmat + ((size_t)bh * 1024 + s) * 64 + lg * 8;
    f32x4 a = {};
    a = MFMA(af[0], *(const bf16x8*)kp, a);
    a = MFMA(af[1], *(const bf16x8*)(kp + 32), a);
#pragma unroll
    for (int r = 0; r < 4; ++r) LS[w][lg * 4 + r][ni * 16 + lr] = f2b(a[r]);
  }
  short* sb = S + ((size_t)bh * 1024 + t0) * 1024 + scol;
  const int r2 = l >> 5, c16 = (l & 31) * 8;
#pragma unroll
  for (int rr = 0; rr < 8; ++rr) {
    int row = rr * 2 + r2;
    bf16x8 o = *(const bf16x8*)&LS[w][row][c16];
    *(bf16x8*)(sb + (size_t)row * 1024 + c16) = o;
  }
}

// ---------------------------------------------------------------------------
// K2b: S = exp(S + q·pos_k + bias - 10) in place (masked -> 0).
// grid (8 s-groups of 128, t); 4 waves x 32 s. LDS 18.7 KB -> 8 blocks/CU.
// All pos_k loads hoisted (128 B/lane in flight).
__global__ __launch_bounds__(256) void k_posk_exp(
    const short* __restrict__ q, const float* __restrict__ pos_k,
    const float* __restrict__ rab, const int* __restrict__ mask,
    short* __restrict__ S) {
  const int t = blockIdx.y;
  const int tid = threadIdx.x;
  const int w = tid >> 6, l = tid & 63, lg = l >> 4, lr = l & 15;
  const int sB = blockIdx.x * 128;
  const int s0 = sB + w * 32;
  __shared__ float RB[16][132];
  __shared__ int MK[2][132];
  __shared__ short SW[4][32][36];

  // ---- issue ALL independent global loads first ----
  float4 PK[2][2][2];
#pragma unroll
  for (int ni = 0; ni < 2; ++ni) {
    int s = s0 + ni * 16 + lr;
#pragma unroll
    for (int kk = 0; kk < 2; ++kk) {
      const float* pk = pos_k + ((size_t)t * 1024 + s) * 64 + kk * 32 + lg * 8;
      PK[ni][kk][0] = *(const float4*)pk;
      PK[ni][kk][1] = *(const float4*)(pk + 4);
    }
  }
  float4 rv[2];
  {
    int hr = tid >> 4, c0 = (tid & 15) * 4;
#pragma unroll
    for (int it = 0; it < 2; ++it)
      rv[it] = *(const float4*)(rab + ((size_t)hr * 1024 + t) * 1024 + sB + c0 + it * 64);
  }
  int4 mv = {1, 1, 1, 1};
  if (tid < 64) {
    int br = tid >> 5, c = (tid & 31) * 4;
    mv = *(const int4*)(mask + ((size_t)br * 1024 + t) * 1024 + sB + c);
  }
  // ---- stage to LDS ----
  {
    int hr = tid >> 4, c0 = (tid & 15) * 4;
#pragma unroll
    for (int it = 0; it < 2; ++it) {
      int c = c0 + it * 64;
      RB[hr][c] = rv[it].x; RB[hr][c + 1] = rv[it].y;
      RB[hr][c + 2] = rv[it].z; RB[hr][c + 3] = rv[it].w;
    }
  }
  if (tid < 64) {
    int br = tid >> 5, c = (tid & 31) * 4;
    MK[br][c] = mv.x; MK[br][c + 1] = mv.y; MK[br][c + 2] = mv.z; MK[br][c + 3] = mv.w;
  }
  {  // stage this wave's S tile: 32 bh rows x 32 s cols (bf16x8)
    int row = l & 31, ch = l >> 5;
#pragma unroll
    for (int rr = 0; rr < 2; ++rr) {
      int c8 = ch * 8 + rr * 16;
      *(bf16x8*)&SW[w][row][c8] =
          *(const bf16x8*)(S + ((size_t)row * 1024 + t) * 1024 + s0 + c8);
    }
  }
  // ---- compute: cvt + MFMA from registers ----
  bf16x8 af[2][2];
#pragma unroll
  for (int mi = 0; mi < 2; ++mi)
#pragma unroll
    for (int kk = 0; kk < 2; ++kk) {
      int bh = mi * 16 + lr;
      af[mi][kk] = *(const bf16x8*)(q + ((size_t)bh * 1024 + t) * 64 + kk * 32 + lg * 8);
    }
  f32x4 acc[2][2] = {};
#pragma unroll
  for (int ni = 0; ni < 2; ++ni) {
#pragma unroll
    for (int kk = 0; kk < 2; ++kk) {
      bf16x8 bfr;
      bfr[0] = f2b(PK[ni][kk][0].x); bfr[1] = f2b(PK[ni][kk][0].y);
      bfr[2] = f2b(PK[ni][kk][0].z); bfr[3] = f2b(PK[ni][kk][0].w);
      bfr[4] = f2b(PK[ni][kk][1].x); bfr[5] = f2b(PK[ni][kk][1].y);
      bfr[6] = f2b(PK[ni][kk][1].z); bfr[7] = f2b(PK[ni][kk][1].w);
#pragma unroll
      for (int mi = 0; mi < 2; ++mi) acc[mi][ni] = MFMA(af[mi][kk], bfr, acc[mi][ni]);
    }
  }
  __syncthreads();
#pragma unroll
  for (int ni = 0; ni < 2; ++ni) {
    int col = ni * 16 + lr;
    int colw = w * 32 + col;
    int msk0 = MK[0][colw];
    int msk1 = MK[1][colw];
#pragma unroll
    for (int r = 0; r < 4; ++r) {
      int h = lg * 4 + r;
      float bv = RB[h][colw];
      float v0 = acc[0][ni][r] + bv + b2f(SW[w][h][col]);
      float v1 = acc[1][ni][r] + bv + b2f(SW[w][16 + h][col]);
      float e0 = (msk0 == 0) ? 0.f : __expf(v0 - 10.f);
      float e1 = (msk1 == 0) ? 0.f : __expf(v1 - 10.f);
      SW[w][h][col] = f2b(e0);
      SW[w][16 + h][col] = f2b(e1);
    }
  }
  {  // write back (per-wave tile)
    int row = l & 31, ch = l >> 5;
#pragma unroll
    for (int rr = 0; rr < 2; ++rr) {
      int c8 = ch * 8 + rr * 16;
      bf16x8 o = *(const bf16x8*)&SW[w][row][c8];
      *(bf16x8*)(S + ((size_t)row * 1024 + t) * 1024 + s0 + c8) = o;
    }
  }
}

// ---------------------------------------------------------------------------
// K3: X0p[qtr] = fp32(eS[:, t, qtr-s] @ pos_v[t, qtr-s]). grid (4, T); 4 waves.
// Double-buffered pvT + issue-early/write-late; 2 chunks of 128 s.
__global__ __launch_bounds__(256) void k_posv(
    const short* __restrict__ S, const float* __restrict__ pos_v,
    float* __restrict__ X0p) {
  const int qtr = blockIdx.x;
  const int t = blockIdx.y;
  const int tid = threadIdx.x;
  const int w = tid >> 6, l = tid & 63, lg = l >> 4, lr = l & 15;
  const int mi = w >> 1;
  const int nb = (w & 1) * 2;
  __shared__ short pvT[2][64][132];
  f32x4 acc[2] = {};
  const int spair = tid >> 4;
  const int dk4 = (tid & 15) * 4;
  const int sbase = qtr * 256;
  float4 ra[4], rb[4];
  // preload + write chunk 0
#pragma unroll
  for (int it = 0; it < 4; ++it) {
    int srel = spair * 2 + it * 32;
    const float* p0 = pos_v + ((size_t)t * 1024 + sbase + srel) * 64 + dk4;
    ra[it] = *(const float4*)p0;
    rb[it] = *(const float4*)(p0 + 64);
  }
#pragma unroll
  for (int it = 0; it < 4; ++it) {
    int srel = spair * 2 + it * 32;
    unsigned u0 = (unsigned)(unsigned short)f2b(ra[it].x) | ((unsigned)(unsigned short)f2b(rb[it].x) << 16);
    unsigned u1 = (unsigned)(unsigned short)f2b(ra[it].y) | ((unsigned)(unsigned short)f2b(rb[it].y) << 16);
    unsigned u2 = (unsigned)(unsigned short)f2b(ra[it].z) | ((unsigned)(unsigned short)f2b(rb[it].z) << 16);
    unsigned u3 = (unsigned)(unsigned short)f2b(ra[it].w) | ((unsigned)(unsigned short)f2b(rb[it].w) << 16);
    *(unsigned*)&pvT[0][dk4 + 0][srel] = u0;
    *(unsigned*)&pvT[0][dk4 + 1][srel] = u1;
    *(unsigned*)&pvT[0][dk4 + 2][srel] = u2;
    *(unsigned*)&pvT[0][dk4 + 3][srel] = u3;
  }
  __syncthreads();
  const int bh = mi * 16 + lr;
  for (int c = 0; c < 2; ++c) {
    const int cur = c & 1;
    if (c < 1) {  // issue next chunk's loads (in flight during MFMA)
#pragma unroll
      for (int it = 0; it < 4; ++it) {
        int srel = spair * 2 + it * 32;
        const float* p0 = pos_v + ((size_t)t * 1024 + sbase + (c + 1) * 128 + srel) * 64 + dk4;
        ra[it] = *(const float4*)p0;
        rb[it] = *(const float4*)(p0 + 64);
      }
    }
    const short* sBp = S + ((size_t)bh * 1024 + t) * 1024 + sbase + c * 128;
#pragma unroll
    for (int kk = 0; kk < 4; ++kk) {
      bf16x8 afr = *(const bf16x8*)(sBp + kk * 32 + lg * 8);
#pragma unroll
      for (int ni = 0; ni < 2; ++ni) {
        int dk = (nb + ni) * 16 + lr;
        const short* pp = &pvT[cur][dk][kk * 32 + lg * 8];
        bf16x4 lo = *(const bf16x4*)pp;
        bf16x4 hi = *(const bf16x4*)(pp + 4);
        bf16x8 bfr;
        bfr[0] = lo[0]; bfr[1] = lo[1]; bfr[2] = lo[2]; bfr[3] = lo[3];
        bfr[4] = hi[0]; bfr[5] = hi[1]; bfr[6] = hi[2]; bfr[7] = hi[3];
        acc[ni] = MFMA(afr, bfr, acc[ni]);
      }
    }
    if (c < 1) {  // write next buffer (disjoint from cur; barrier before reuse)
#pragma unroll
      for (int it = 0; it < 4; ++it) {
        int srel = spair * 2 + it * 32;
        unsigned u0 = (unsigned)(unsigned short)f2b(ra[it].x) | ((unsigned)(unsigned short)f2b(rb[it].x) << 16);
        unsigned u1 = (unsigned)(unsigned short)f2b(ra[it].y) | ((unsigned)(unsigned short)f2b(rb[it].y) << 16);
        unsigned u2 = (unsigned)(unsigned short)f2b(ra[it].z) | ((unsigned)(unsigned short)f2b(rb[it].z) << 16);
        unsigned u3 = (unsigned)(unsigned short)f2b(ra[it].w) | ((unsigned)(unsigned short)f2b(rb[it].w) << 16);
        *(unsigned*)&pvT[cur ^ 1][dk4 + 0][srel] = u0;
        *(unsigned*)&pvT[cur ^ 1][dk4 + 1][srel] = u1;
        *(unsigned*)&pvT[cur ^ 1][dk4 + 2][srel] = u2;
        *(unsigned*)&pvT[cur ^ 1][dk4 + 3][srel] = u3;
      }
      __syncthreads();
    }
  }
#pragma unroll
  for (int ni = 0; ni < 2; ++ni)
#pragma unroll
    for (int r = 0; r < 4; ++r) {
      int bh2 = mi * 16 + lg * 4 + r;
      int b = bh2 >> 4, h = bh2 & 15;
      int dk = (nb + ni) * 16 + lr;
      X0p[((size_t)qtr << 21) + ((size_t)(b * 1024 + t)) * 1024 + h * 64 + dk] =
          acc[ni][r];
    }
}

// ---------------------------------------------------------------------------
// K4: X = bf16((sum_q X0p[q] + eS @ v) / l), l = row-sum of eS computed inline.
__global__ __launch_bounds__(256) void k_av(
    const short* __restrict__ S, const short* __restrict__ vT,
    const float* __restrict__ X0p, short* __restrict__ X) {
  const int bh = blockIdx.y;
  const int tt0 = blockIdx.x * 32;
  const int tid = threadIdx.x;
  const int w = tid >> 6, l = tid & 63, lg = l >> 4, lr = l & 15;
  const int wm = w >> 1, wn = w & 1;
  const short* vbase = vT + ((size_t)bh << 16) + ((size_t)(wn * 32) << 10);
  const short* sbase = S + ((size_t)bh << 20) + ((size_t)(tt0 + wm * 16) << 10);
  f32x4 acc[2] = {};
  float lsum = 0.f;
#pragma unroll 8
  for (int kk = 0; kk < 32; ++kk) {
    bf16x8 afr = *(const bf16x8*)(sbase + ((size_t)lr << 10) + kk * 32 + lg * 8);
#pragma unroll
    for (int j = 0; j < 8; ++j) lsum += b2f(afr[j]);
#pragma unroll
    for (int ni = 0; ni < 2; ++ni) {
      bf16x8 bfr = *(const bf16x8*)(vbase + ((size_t)(ni * 16 + lr) << 10) + kk * 32 + lg * 8);
      acc[ni] = MFMA(afr, bfr, acc[ni]);
    }
  }
  lsum += __shfl_xor(lsum, 16);
  lsum += __shfl_xor(lsum, 32);
  const int b = bh >> 4, h = bh & 15;
#pragma unroll
  for (int ni = 0; ni < 2; ++ni)
#pragma unroll
    for (int r = 0; r < 4; ++r) {
      float lrow = __shfl(lsum, lg * 4 + r);
      float inv = 1.0f / lrow;
      int tt = tt0 + wm * 16 + lg * 4 + r;
      int d = h * 64 + wn * 32 + ni * 16 + lr;
      size_t idx = ((size_t)(b * 1024 + tt)) * 1024 + d;
      float x0 = X0p[idx] + X0p[idx + (1ull << 21)] +
                 X0p[idx + (2ull << 21)] + X0p[idx + (3ull << 21)];
      X[idx] = f2b((x0 + acc[ni][r]) * inv);
    }
}

// ---------------------------------------------------------------------------
// K5: out = X @ Wo + bo (fp32). 64x64 tile, BK=32, grid (16,32).
__global__ __launch_bounds__(256) void k_oproj(
    const short* __restrict__ X, const short* __restrict__ WT,
    const float* __restrict__ bias, float* __restrict__ out) {
  __shared__ short As[64 * 32];
  __shared__ short Bs[64 * 32];
  const int tid = threadIdx.x;
  const int w = tid >> 6, l = tid & 63, lg = l >> 4, lr = l & 15;
  const int wm = w >> 1, wn = w & 1;
  const int n0 = blockIdx.x * 64;
  const int m0 = blockIdx.y * 64;
  const short* Abase = X + ((size_t)m0 << 10);
  const short* Bbase = WT + ((size_t)n0 << 10);
  const int srow = l >> 2, scol8 = (l & 3) * 8;
  f32x4 acc[2][2] = {};
  for (int k0 = 0; k0 < 1024; k0 += 32) {
    gload16(Abase + (size_t)(w * 16 + srow) * 1024 + k0 + scol8, &As[w * 512]);
    gload16(Bbase + (size_t)(w * 16 + srow) * 1024 + k0 + scol8, &Bs[w * 512]);
    __syncthreads();
    bf16x8 af[2], bf[2];
#pragma unroll
    for (int i = 0; i < 2; ++i) af[i] = *(const bf16x8*)&As[(wm * 32 + i * 16 + lr) * 32 + lg * 8];
#pragma unroll
    for (int i = 0; i < 2; ++i) bf[i] = *(const bf16x8*)&Bs[(wn * 32 + i * 16 + lr) * 32 + lg * 8];
#pragma unroll
    for (int mi = 0; mi < 2; ++mi)
#pragma unroll
      for (int ni = 0; ni < 2; ++ni) acc[mi][ni] = MFMA(af[mi], bf[ni], acc[mi][ni]);
    __syncthreads();
  }
  float bvals[2];
#pragma unroll
  for (int ni = 0; ni < 2; ++ni) bvals[ni] = bias[n0 + wn * 32 + ni * 16 + lr];
#pragma unroll
  for (int mi = 0; mi < 2; ++mi)
#pragma unroll
    for (int ni = 0; ni < 2; ++ni)
#pragma unroll
      for (int r = 0; r < 4; ++r) {
        int m = m0 + wm * 32 + mi * 16 + lg * 4 + r;
        int n = n0 + wn * 32 + ni * 16 + lr;
        out[(size_t)m * 1024 + n] = acc[mi][ni][r] + bvals[ni];
      }
}

// ---------------------------------------------------------------------------
extern "C" void kernel_launch(void* const* d_in, const int* in_sizes, int n_in,
                              void* d_out, int out_size, void* d_ws, size_t ws_size,
                              hipStream_t stream) {
  (void)in_sizes; (void)n_in; (void)out_size; (void)ws_size;
  const float* query = (const float*)d_in[0];
  const float* key   = (const float*)d_in[1];
  const float* value = (const float*)d_in[2];
  const float* pos_k = (const float*)d_in[3];
  const float* pos_v = (const float*)d_in[4];
  const int*   mask  = (const int*)d_in[5];
  const float* rab   = (const float*)d_in[6];
  const float* Wq = (const float*)d_in[7];
  const float* bq = (const float*)d_in[8];
  const float* Wk = (const float*)d_in[9];
  const float* bk = (const float*)d_in[10];
  const float* Wv = (const float*)d_in[11];
  const float* bv = (const float*)d_in[12];
  const float* Wo = (const float*)d_in[13];
  const float* bo = (const float*)d_in[14];
  float* out = (float*)d_out;

  const size_t M2 = 2ull * 1024 * 1024;  // B*T*D elements
  short* q   = (short*)d_ws;
  short* k   = q + M2;
  short* vT  = k + M2;                    // [bh][dk][t]
  short* S   = vT + M2;                   // 32M bf16: raw scores then eS (in place)
  float* X0p = (float*)(S + 32ull * 1024 * 1024);  // 4 quarters x 2M f32 (32 MB)
  short* X   = (short*)(X0p + 4 * M2);
  short* qin = X + M2;                    // stacked [3][2048][1024]
  short* kin = qin + M2;
  short* vin = kin + M2;
  short* WqT = vin + M2;                  // stacked [3+1][1024][1024]
  short* WkT = WqT + 1024 * 1024;
  short* WvT = WkT + 1024 * 1024;
  short* WoT = WvT + 1024 * 1024;

  k_cvt3<<<dim3(1024, 3), dim3(256), 0, stream>>>(query, key, value, qin, kin, vin);
  k_wtrans4<<<dim3(16, 16, 4), dim3(256), 0, stream>>>(Wq, Wk, Wv, Wo, WqT, WkT, WvT, WoT);
  k_qkv<<<dim3(16, 48), dim3(256), 0, stream>>>(qin, WqT, bq, bk, bv, q, k, vT);
  k_qk<<<dim3(32, 32), dim3(512), 0, stream>>>(q, k, S);
  k_posk_exp<<<dim3(8, 1024), dim3(256), 0, stream>>>(q, pos_k, rab, mask, S);
  k_posv<<<dim3(4, 1024), dim3(256), 0, stream>>>(S, pos_v, X0p);
  k_av<<<dim3(32, 32), dim3(256), 0, stream>>>(S, vT, X0p, X);
  k_oproj<<<dim3(16, 32), dim3(256), 0, stream>>>(X, WoT, bo, out);
}

// Round 16
// 301.947 us; speedup vs baseline: 1.2359x; 1.0423x over previous
//
#include <hip/hip_runtime.h>

// MultiHeadedAttention with relative position (B=2, T=1024, D=1024, H=16, DK=64)
// Pipeline: cvt(inputs->bf16), wtrans(W->bf16 [n][k]) -> fused QKV GEMM (XCD-swizzled) ->
//   k_qk: S = q@k^T (raw, bf16) -> k_posk_exp: S = exp(S + Bp + bias - 10) in place
//   (masked -> 0; ALL pos_k loads hoisted for deep MLP) ->
//   X0p[2] = eS@pos_v halves (double-buffered LDS, issue-early/write-late) ->
//   X = (X0p0 + X0p1 + eS@v)/l (l inline) -> out = X@Wo+bo.
// [R16 = exact revert to R11, the measured optimum of 12 structural variants.]

#define DEV __device__ __forceinline__

typedef short bf16x8 __attribute__((ext_vector_type(8)));
typedef short bf16x4 __attribute__((ext_vector_type(4)));
typedef float f32x4 __attribute__((ext_vector_type(4)));

DEV short f2b(float f) {
  unsigned u = __builtin_bit_cast(unsigned, f);
  u = (u + 0x7FFFu + ((u >> 16) & 1u)) >> 16;
  return (short)u;
}
DEV float b2f(short s) {
  unsigned u = ((unsigned)(unsigned short)s) << 16;
  return __builtin_bit_cast(float, u);
}

#define MFMA(a, b, c) __builtin_amdgcn_mfma_f32_16x16x32_bf16(a, b, c, 0, 0, 0)

DEV void gload16(const void* g, void* l) {
  __builtin_amdgcn_global_load_lds(
      (const __attribute__((address_space(1))) void*)g,
      (__attribute__((address_space(3))) void*)l, 16, 0, 0);
}

// ---------------------------------------------------------------------------
// P1: fp32 -> bf16 flat convert for query/key/value.
__global__ __launch_bounds__(256) void k_cvt3(
    const float* __restrict__ a, const float* __restrict__ b, const float* __restrict__ c,
    short* __restrict__ oa, short* __restrict__ ob, short* __restrict__ oc) {
  const float* src = blockIdx.y == 0 ? a : (blockIdx.y == 1 ? b : c);
  short* dst = blockIdx.y == 0 ? oa : (blockIdx.y == 1 ? ob : oc);
  size_t i = ((size_t)blockIdx.x * 256 + threadIdx.x) * 8;
  float4 p0 = *(const float4*)(src + i);
  float4 p1 = *(const float4*)(src + i + 4);
  bf16x8 o;
  o[0] = f2b(p0.x); o[1] = f2b(p0.y); o[2] = f2b(p0.z); o[3] = f2b(p0.w);
  o[4] = f2b(p1.x); o[5] = f2b(p1.y); o[6] = f2b(p1.z); o[7] = f2b(p1.w);
  *(bf16x8*)(dst + i) = o;
}

// P2: W [k][n] fp32 -> WT [n][k] bf16, 64x64 tiles via LDS.
__global__ __launch_bounds__(256) void k_wtrans4(
    const float* __restrict__ w0, const float* __restrict__ w1,
    const float* __restrict__ w2, const float* __restrict__ w3,
    short* __restrict__ o0, short* __restrict__ o1,
    short* __restrict__ o2, short* __restrict__ o3) {
  const float* src; short* dst;
  switch (blockIdx.z) {
    case 0: src = w0; dst = o0; break;
    case 1: src = w1; dst = o1; break;
    case 2: src = w2; dst = o2; break;
    default: src = w3; dst = o3;
  }
  __shared__ short LW[64][74];
  const int tid = threadIdx.x;
  const int k0 = blockIdx.y * 64, n0 = blockIdx.x * 64;
  {
    int c4 = (tid & 15) * 4;
#pragma unroll
    for (int i = 0; i < 4; ++i) {
      int r = (tid >> 4) + i * 16;
      float4 v = *(const float4*)(src + (size_t)(k0 + r) * 1024 + n0 + c4);
      LW[r][c4 + 0] = f2b(v.x); LW[r][c4 + 1] = f2b(v.y);
      LW[r][c4 + 2] = f2b(v.z); LW[r][c4 + 3] = f2b(v.w);
    }
  }
  __syncthreads();
  {
    int n = tid >> 2, kb = (tid & 3) * 16;
#pragma unroll
    for (int j2 = 0; j2 < 2; ++j2) {
      int kk = kb + j2 * 8;
      bf16x8 o;
#pragma unroll
      for (int j = 0; j < 8; ++j) o[j] = LW[kk + j][n];
      *(bf16x8*)(dst + (size_t)(n0 + n) * 1024 + k0 + kk) = o;
    }
  }
}

// ---------------------------------------------------------------------------
// K1: fused QKV projection with bijective XCD chunk-swizzle.
__global__ __launch_bounds__(256) void k_qkv(
    const short* __restrict__ Ain, const short* __restrict__ WT,
    const float* __restrict__ bq, const float* __restrict__ bk,
    const float* __restrict__ bv,
    short* __restrict__ qo, short* __restrict__ ko, short* __restrict__ vTo) {
  __shared__ short As[128 * 32];
  __shared__ short Bs[64 * 32];
  __shared__ short LW[128][72];
  const int tid = threadIdx.x;
  const int w = tid >> 6, l = tid & 63, lg = l >> 4, lr = l & 15;
  const int wm = w >> 1, wn = w & 1;
  const int flat = blockIdx.x + gridDim.x * blockIdx.y;  // 0..767
  const int flat2 = (flat & 7) * 96 + (flat >> 3);
  const int n0 = (flat2 & 15) * 64;
  const int m0 = (flat2 >> 4) * 128;
  const int seg = m0 >> 11;
  const int mseg = m0 & 2047;
  const short* Abase = Ain + ((size_t)m0 << 10);
  const short* Bbase = WT + ((size_t)seg << 20) + ((size_t)n0 << 10);
  const int srow = l >> 2, scol8 = (l & 3) * 8;
  f32x4 acc[4][2] = {};
  for (int k0 = 0; k0 < 1024; k0 += 32) {
    gload16(Abase + (size_t)((w * 2) * 16 + srow) * 1024 + k0 + scol8, &As[(w * 2) * 512]);
    gload16(Abase + (size_t)((w * 2 + 1) * 16 + srow) * 1024 + k0 + scol8, &As[(w * 2 + 1) * 512]);
    gload16(Bbase + (size_t)(w * 16 + srow) * 1024 + k0 + scol8, &Bs[w * 512]);
    __syncthreads();
    bf16x8 af[4], bf[2];
#pragma unroll
    for (int i = 0; i < 4; ++i) af[i] = *(const bf16x8*)&As[(wm * 64 + i * 16 + lr) * 32 + lg * 8];
#pragma unroll
    for (int i = 0; i < 2; ++i) bf[i] = *(const bf16x8*)&Bs[(wn * 32 + i * 16 + lr) * 32 + lg * 8];
#pragma unroll
    for (int mi = 0; mi < 4; ++mi)
#pragma unroll
      for (int ni = 0; ni < 2; ++ni) acc[mi][ni] = MFMA(af[mi], bf[ni], acc[mi][ni]);
    __syncthreads();
  }
  const float* bias = seg == 0 ? bq : (seg == 1 ? bk : bv);
  const float scale = seg == 0 ? 0.125f : 1.0f;
  float bvals[2];
#pragma unroll
  for (int ni = 0; ni < 2; ++ni) bvals[ni] = bias[n0 + wn * 32 + ni * 16 + lr];
#pragma unroll
  for (int mi = 0; mi < 4; ++mi)
#pragma unroll
    for (int ni = 0; ni < 2; ++ni)
#pragma unroll
      for (int r = 0; r < 4; ++r)
        LW[wm * 64 + mi * 16 + lg * 4 + r][wn * 32 + ni * 16 + lr] =
            f2b((acc[mi][ni][r] + bvals[ni]) * scale);
  __syncthreads();
  if (seg < 2) {
    short* dst = seg == 0 ? qo : ko;
    int r = tid >> 1, half = tid & 1;
    int m = mseg + r, b = m >> 10, t = m & 1023;
    int h = n0 >> 6;
#pragma unroll
    for (int g = 0; g < 4; ++g) {
      int dk = half * 32 + g * 8;
      bf16x8 o = *(const bf16x8*)&LW[r][dk];
      *(bf16x8*)(dst + (((size_t)(b * 16 + h) * 1024 + t) << 6) + dk) = o;
    }
  } else {
    int dkc = tid & 63, th = tid >> 6;
    int h = n0 >> 6, dk = dkc;
    int b = mseg >> 10;
    int tbase = (mseg & 1023) + th * 32;
#pragma unroll
    for (int g = 0; g < 4; ++g) {
      bf16x8 o;
#pragma unroll
      for (int e = 0; e < 8; ++e) o[e] = LW[th * 32 + g * 8 + e][dkc];
      *(bf16x8*)(vTo + (((size_t)(b * 16 + h) * 64 + dk) << 10) + tbase + g * 8) = o;
    }
  }
}

// ---------------------------------------------------------------------------
// K2a: S = q@k^T raw scores (bf16). grid (T/32, bh); 8 waves, wave 16t x 256s.
__global__ __launch_bounds__(512, 2) void k_qk(
    const short* __restrict__ q, const short* __restrict__ kmat,
    short* __restrict__ S) {
  const int bh = blockIdx.y;
  const int tid = threadIdx.x;
  const int w = tid >> 6, l = tid & 63, lg = l >> 4, lr = l & 15;
  const int wm = w >> 2, wn = w & 3;
  const int t0 = blockIdx.x * 32 + wm * 16;
  const int scol = wn * 256;
  __shared__ short LS[8][16][266];

  bf16x8 af[2];
#pragma unroll
  for (int kk = 0; kk < 2; ++kk)
    af[kk] = *(const bf16x8*)(q + ((size_t)bh * 1024 + (t0 + lr)) * 64 + kk * 32 + lg * 8);

#pragma unroll
  for (int ni = 0; ni < 16; ++ni) {
    int s = scol + ni * 16 + lr;
    const short* kp = kmat + ((size_t)bh * 1024 + s) * 64 + lg * 8;
    f32x4 a = {};
    a = MFMA(af[0], *(const bf16x8*)kp, a);
    a = MFMA(af[1], *(const bf16x8*)(kp + 32), a);
#pragma unroll
    for (int r = 0; r < 4; ++r) LS[w][lg * 4 + r][ni * 16 + lr] = f2b(a[r]);
  }
  short* sb = S + ((size_t)bh * 1024 + t0) * 1024 + scol;
  const int r2 = l >> 5, c16 = (l & 31) * 8;
#pragma unroll
  for (int rr = 0; rr < 8; ++rr) {
    int row = rr * 2 + r2;
    bf16x8 o = *(const bf16x8*)&LS[w][row][c16];
    *(bf16x8*)(sb + (size_t)row * 1024 + c16) = o;
  }
}

// ---------------------------------------------------------------------------
// K2b: S = exp(S + q·pos_k + bias - 10) in place (masked -> 0).
// ALL 16 pos_k float4 loads hoisted to registers before compute: 256 B/lane
// in flight (vs ~32 B with interleaved load/use) -> latency-bound fix.
__global__ __launch_bounds__(256) void k_posk_exp(
    const short* __restrict__ q, const float* __restrict__ pos_k,
    const float* __restrict__ rab, const int* __restrict__ mask,
    short* __restrict__ S) {
  const int t = blockIdx.y;
  const int tid = threadIdx.x;
  const int w = tid >> 6, l = tid & 63, lg = l >> 4, lr = l & 15;
  const int sB = blockIdx.x * 256;
  const int s0 = sB + w * 64;
  __shared__ float RB[16][260];
  __shared__ int MK[2][260];
  __shared__ short SW[4][32][66];

  // ---- issue ALL independent global loads first ----
  float4 PK[4][2][2];  // [ni][kk][pair] -- fully unrolled, constant indices
#pragma unroll
  for (int ni = 0; ni < 4; ++ni) {
    int s = s0 + ni * 16 + lr;
#pragma unroll
    for (int kk = 0; kk < 2; ++kk) {
      const float* pk = pos_k + ((size_t)t * 1024 + s) * 64 + kk * 32 + lg * 8;
      PK[ni][kk][0] = *(const float4*)pk;
      PK[ni][kk][1] = *(const float4*)(pk + 4);
    }
  }
  float4 rv[4];
  {
    int hr = tid >> 4, c0 = (tid & 15) * 4;
#pragma unroll
    for (int it = 0; it < 4; ++it)
      rv[it] = *(const float4*)(rab + ((size_t)hr * 1024 + t) * 1024 + sB + c0 + it * 64);
  }
  int4 mv = {1, 1, 1, 1};
  if (tid < 128) {
    int br = tid >> 6, c = (tid & 63) * 4;
    mv = *(const int4*)(mask + ((size_t)br * 1024 + t) * 1024 + sB + c);
  }
  // ---- stage to LDS ----
  {
    int hr = tid >> 4, c0 = (tid & 15) * 4;
#pragma unroll
    for (int it = 0; it < 4; ++it) {
      int c = c0 + it * 64;
      RB[hr][c] = rv[it].x; RB[hr][c + 1] = rv[it].y;
      RB[hr][c + 2] = rv[it].z; RB[hr][c + 3] = rv[it].w;
    }
  }
  if (tid < 128) {
    int br = tid >> 6, c = (tid & 63) * 4;
    MK[br][c] = mv.x; MK[br][c + 1] = mv.y; MK[br][c + 2] = mv.z; MK[br][c + 3] = mv.w;
  }
  {  // stage this wave's S tile (wave-private region)
#pragma unroll
    for (int rr = 0; rr < 4; ++rr) {
      int row = (l >> 3) + rr * 8;
      int s8 = (l & 7) * 8;
      *(bf16x8*)&SW[w][row][s8] =
          *(const bf16x8*)(S + ((size_t)row * 1024 + t) * 1024 + s0 + s8);
    }
  }
  // ---- compute: cvt + MFMA from registers ----
  bf16x8 af[2][2];
#pragma unroll
  for (int mi = 0; mi < 2; ++mi)
#pragma unroll
    for (int kk = 0; kk < 2; ++kk) {
      int bh = mi * 16 + lr;
      af[mi][kk] = *(const bf16x8*)(q + ((size_t)bh * 1024 + t) * 64 + kk * 32 + lg * 8);
    }
  f32x4 acc[2][4] = {};
#pragma unroll
  for (int ni = 0; ni < 4; ++ni) {
#pragma unroll
    for (int kk = 0; kk < 2; ++kk) {
      bf16x8 bfr;
      bfr[0] = f2b(PK[ni][kk][0].x); bfr[1] = f2b(PK[ni][kk][0].y);
      bfr[2] = f2b(PK[ni][kk][0].z); bfr[3] = f2b(PK[ni][kk][0].w);
      bfr[4] = f2b(PK[ni][kk][1].x); bfr[5] = f2b(PK[ni][kk][1].y);
      bfr[6] = f2b(PK[ni][kk][1].z); bfr[7] = f2b(PK[ni][kk][1].w);
#pragma unroll
      for (int mi = 0; mi < 2; ++mi) acc[mi][ni] = MFMA(af[mi][kk], bfr, acc[mi][ni]);
    }
  }
  __syncthreads();
#pragma unroll
  for (int ni = 0; ni < 4; ++ni) {
    int colw = w * 64 + ni * 16 + lr;
    int col = ni * 16 + lr;
    int msk0 = MK[0][colw];
    int msk1 = MK[1][colw];
#pragma unroll
    for (int r = 0; r < 4; ++r) {
      int h = lg * 4 + r;
      float bv = RB[h][colw];
      float v0 = acc[0][ni][r] + bv + b2f(SW[w][h][col]);
      float v1 = acc[1][ni][r] + bv + b2f(SW[w][16 + h][col]);
      float e0 = (msk0 == 0) ? 0.f : __expf(v0 - 10.f);
      float e1 = (msk1 == 0) ? 0.f : __expf(v1 - 10.f);
      SW[w][h][col] = f2b(e0);
      SW[w][16 + h][col] = f2b(e1);
    }
  }
#pragma unroll
  for (int rr = 0; rr < 4; ++rr) {
    int row = (l >> 3) + rr * 8;
    int s8 = (l & 7) * 8;
    bf16x8 o = *(const bf16x8*)&SW[w][row][s8];
    *(bf16x8*)(S + ((size_t)row * 1024 + t) * 1024 + s0 + s8) = o;
  }
}

// ---------------------------------------------------------------------------
// K3: X0p[half] = fp32(eS[:, t, half-s] @ pos_v[t, half-s]). grid (2, T); 4 waves.
// Double-buffered pvT + issue-early/write-late: chunk c+1 loads issue before
// MFMA(c), LDS write lands after (HBM latency hidden under MFMA). 1 barrier/chunk.
__global__ __launch_bounds__(256) void k_posv(
    const short* __restrict__ S, const float* __restrict__ pos_v,
    float* __restrict__ X0p) {
  const int half = blockIdx.x;
  const int t = blockIdx.y;
  const int tid = threadIdx.x;
  const int w = tid >> 6, l = tid & 63, lg = l >> 4, lr = l & 15;
  const int mi = w >> 1;
  const int nb = (w & 1) * 2;
  __shared__ short pvT[2][64][132];
  f32x4 acc[2] = {};
  const int spair = tid >> 4;
  const int dk4 = (tid & 15) * 4;
  const int sbase = half * 512;
  float4 ra[4], rb[4];
  // preload + write chunk 0
#pragma unroll
  for (int it = 0; it < 4; ++it) {
    int srel = spair * 2 + it * 32;
    const float* p0 = pos_v + ((size_t)t * 1024 + sbase + srel) * 64 + dk4;
    ra[it] = *(const float4*)p0;
    rb[it] = *(const float4*)(p0 + 64);
  }
#pragma unroll
  for (int it = 0; it < 4; ++it) {
    int srel = spair * 2 + it * 32;
    unsigned u0 = (unsigned)(unsigned short)f2b(ra[it].x) | ((unsigned)(unsigned short)f2b(rb[it].x) << 16);
    unsigned u1 = (unsigned)(unsigned short)f2b(ra[it].y) | ((unsigned)(unsigned short)f2b(rb[it].y) << 16);
    unsigned u2 = (unsigned)(unsigned short)f2b(ra[it].z) | ((unsigned)(unsigned short)f2b(rb[it].z) << 16);
    unsigned u3 = (unsigned)(unsigned short)f2b(ra[it].w) | ((unsigned)(unsigned short)f2b(rb[it].w) << 16);
    *(unsigned*)&pvT[0][dk4 + 0][srel] = u0;
    *(unsigned*)&pvT[0][dk4 + 1][srel] = u1;
    *(unsigned*)&pvT[0][dk4 + 2][srel] = u2;
    *(unsigned*)&pvT[0][dk4 + 3][srel] = u3;
  }
  __syncthreads();
  const int bh = mi * 16 + lr;
  for (int c = 0; c < 4; ++c) {
    const int cur = c & 1;
    if (c < 3) {  // issue next chunk's loads (in flight during MFMA)
#pragma unroll
      for (int it = 0; it < 4; ++it) {
        int srel = spair * 2 + it * 32;
        const float* p0 = pos_v + ((size_t)t * 1024 + sbase + (c + 1) * 128 + srel) * 64 + dk4;
        ra[it] = *(const float4*)p0;
        rb[it] = *(const float4*)(p0 + 64);
      }
    }
    const short* sBp = S + ((size_t)bh * 1024 + t) * 1024 + sbase + c * 128;
#pragma unroll
    for (int kk = 0; kk < 4; ++kk) {
      bf16x8 afr = *(const bf16x8*)(sBp + kk * 32 + lg * 8);
#pragma unroll
      for (int ni = 0; ni < 2; ++ni) {
        int dk = (nb + ni) * 16 + lr;
        const short* pp = &pvT[cur][dk][kk * 32 + lg * 8];
        bf16x4 lo = *(const bf16x4*)pp;
        bf16x4 hi = *(const bf16x4*)(pp + 4);
        bf16x8 bfr;
        bfr[0] = lo[0]; bfr[1] = lo[1]; bfr[2] = lo[2]; bfr[3] = lo[3];
        bfr[4] = hi[0]; bfr[5] = hi[1]; bfr[6] = hi[2]; bfr[7] = hi[3];
        acc[ni] = MFMA(afr, bfr, acc[ni]);
      }
    }
    if (c < 3) {  // write next buffer (disjoint from cur; barrier before reuse)
#pragma unroll
      for (int it = 0; it < 4; ++it) {
        int srel = spair * 2 + it * 32;
        unsigned u0 = (unsigned)(unsigned short)f2b(ra[it].x) | ((unsigned)(unsigned short)f2b(rb[it].x) << 16);
        unsigned u1 = (unsigned)(unsigned short)f2b(ra[it].y) | ((unsigned)(unsigned short)f2b(rb[it].y) << 16);
        unsigned u2 = (unsigned)(unsigned short)f2b(ra[it].z) | ((unsigned)(unsigned short)f2b(rb[it].z) << 16);
        unsigned u3 = (unsigned)(unsigned short)f2b(ra[it].w) | ((unsigned)(unsigned short)f2b(rb[it].w) << 16);
        *(unsigned*)&pvT[cur ^ 1][dk4 + 0][srel] = u0;
        *(unsigned*)&pvT[cur ^ 1][dk4 + 1][srel] = u1;
        *(unsigned*)&pvT[cur ^ 1][dk4 + 2][srel] = u2;
        *(unsigned*)&pvT[cur ^ 1][dk4 + 3][srel] = u3;
      }
      __syncthreads();
    }
  }
#pragma unroll
  for (int ni = 0; ni < 2; ++ni)
#pragma unroll
    for (int r = 0; r < 4; ++r) {
      int bh2 = mi * 16 + lg * 4 + r;
      int b = bh2 >> 4, h = bh2 & 15;
      int dk = (nb + ni) * 16 + lr;
      X0p[((size_t)half << 21) + ((size_t)(b * 1024 + t)) * 1024 + h * 64 + dk] =
          acc[ni][r];
    }
}

// ---------------------------------------------------------------------------
// K4: X = bf16((X0p0 + X0p1 + eS @ v) / l), l = row-sum of eS computed inline.
__global__ __launch_bounds__(256) void k_av(
    const short* __restrict__ S, const short* __restrict__ vT,
    const float* __restrict__ X0p, short* __restrict__ X) {
  const int bh = blockIdx.y;
  const int tt0 = blockIdx.x * 32;
  const int tid = threadIdx.x;
  const int w = tid >> 6, l = tid & 63, lg = l >> 4, lr = l & 15;
  const int wm = w >> 1, wn = w & 1;
  const short* vbase = vT + ((size_t)bh << 16) + ((size_t)(wn * 32) << 10);
  const short* sbase = S + ((size_t)bh << 20) + ((size_t)(tt0 + wm * 16) << 10);
  f32x4 acc[2] = {};
  float lsum = 0.f;
#pragma unroll 8
  for (int kk = 0; kk < 32; ++kk) {
    bf16x8 afr = *(const bf16x8*)(sbase + ((size_t)lr << 10) + kk * 32 + lg * 8);
#pragma unroll
    for (int j = 0; j < 8; ++j) lsum += b2f(afr[j]);
#pragma unroll
    for (int ni = 0; ni < 2; ++ni) {
      bf16x8 bfr = *(const bf16x8*)(vbase + ((size_t)(ni * 16 + lr) << 10) + kk * 32 + lg * 8);
      acc[ni] = MFMA(afr, bfr, acc[ni]);
    }
  }
  lsum += __shfl_xor(lsum, 16);
  lsum += __shfl_xor(lsum, 32);
  const int b = bh >> 4, h = bh & 15;
#pragma unroll
  for (int ni = 0; ni < 2; ++ni)
#pragma unroll
    for (int r = 0; r < 4; ++r) {
      float lrow = __shfl(lsum, lg * 4 + r);
      float inv = 1.0f / lrow;
      int tt = tt0 + wm * 16 + lg * 4 + r;
      int d = h * 64 + wn * 32 + ni * 16 + lr;
      size_t idx = ((size_t)(b * 1024 + tt)) * 1024 + d;
      X[idx] = f2b((X0p[idx] + X0p[idx + (1u << 21)] + acc[ni][r]) * inv);
    }
}

// ---------------------------------------------------------------------------
// K5: out = X @ Wo + bo (fp32). 64x64 tile, BK=32, grid (16,32).
__global__ __launch_bounds__(256) void k_oproj(
    const short* __restrict__ X, const short* __restrict__ WT,
    const float* __restrict__ bias, float* __restrict__ out) {
  __shared__ short As[64 * 32];
  __shared__ short Bs[64 * 32];
  const int tid = threadIdx.x;
  const int w = tid >> 6, l = tid & 63, lg = l >> 4, lr = l & 15;
  const int wm = w >> 1, wn = w & 1;
  const int n0 = blockIdx.x * 64;
  const int m0 = blockIdx.y * 64;
  const short* Abase = X + ((size_t)m0 << 10);
  const short* Bbase = WT + ((size_t)n0 << 10);
  const int srow = l >> 2, scol8 = (l & 3) * 8;
  f32x4 acc[2][2] = {};
  for (int k0 = 0; k0 < 1024; k0 += 32) {
    gload16(Abase + (size_t)(w * 16 + srow) * 1024 + k0 + scol8, &As[w * 512]);
    gload16(Bbase + (size_t)(w * 16 + srow) * 1024 + k0 + scol8, &Bs[w * 512]);
    __syncthreads();
    bf16x8 af[2], bf[2];
#pragma unroll
    for (int i = 0; i < 2; ++i) af[i] = *(const bf16x8*)&As[(wm * 32 + i * 16 + lr) * 32 + lg * 8];
#pragma unroll
    for (int i = 0; i < 2; ++i) bf[i] = *(const bf16x8*)&Bs[(wn * 32 + i * 16 + lr) * 32 + lg * 8];
#pragma unroll
    for (int mi = 0; mi < 2; ++mi)
#pragma unroll
      for (int ni = 0; ni < 2; ++ni) acc[mi][ni] = MFMA(af[mi], bf[ni], acc[mi][ni]);
    __syncthreads();
  }
  float bvals[2];
#pragma unroll
  for (int ni = 0; ni < 2; ++ni) bvals[ni] = bias[n0 + wn * 32 + ni * 16 + lr];
#pragma unroll
  for (int mi = 0; mi < 2; ++mi)
#pragma unroll
    for (int ni = 0; ni < 2; ++ni)
#pragma unroll
      for (int r = 0; r < 4; ++r) {
        int m = m0 + wm * 32 + mi * 16 + lg * 4 + r;
        int n = n0 + wn * 32 + ni * 16 + lr;
        out[(size_t)m * 1024 + n] = acc[mi][ni][r] + bvals[ni];
      }
}

// ---------------------------------------------------------------------------
extern "C" void kernel_launch(void* const* d_in, const int* in_sizes, int n_in,
                              void* d_out, int out_size, void* d_ws, size_t ws_size,
                              hipStream_t stream) {
  (void)in_sizes; (void)n_in; (void)out_size; (void)ws_size;
  const float* query = (const float*)d_in[0];
  const float* key   = (const float*)d_in[1];
  const float* value = (const float*)d_in[2];
  const float* pos_k = (const float*)d_in[3];
  const float* pos_v = (const float*)d_in[4];
  const int*   mask  = (const int*)d_in[5];
  const float* rab   = (const float*)d_in[6];
  const float* Wq = (const float*)d_in[7];
  const float* bq = (const float*)d_in[8];
  const float* Wk = (const float*)d_in[9];
  const float* bk = (const float*)d_in[10];
  const float* Wv = (const float*)d_in[11];
  const float* bv = (const float*)d_in[12];
  const float* Wo = (const float*)d_in[13];
  const float* bo = (const float*)d_in[14];
  float* out = (float*)d_out;

  const size_t M2 = 2ull * 1024 * 1024;  // B*T*D elements
  short* q   = (short*)d_ws;
  short* k   = q + M2;
  short* vT  = k + M2;                    // [bh][dk][t]
  short* S   = vT + M2;                   // 32M bf16: raw scores then eS (in place)
  float* X0p = (float*)(S + 32ull * 1024 * 1024);  // 2 halves x 2M f32 (16 MB)
  short* X   = (short*)(X0p + 2 * M2);
  short* qin = X + M2;                    // stacked [3][2048][1024]
  short* kin = qin + M2;
  short* vin = kin + M2;
  short* WqT = vin + M2;                  // stacked [3+1][1024][1024]
  short* WkT = WqT + 1024 * 1024;
  short* WvT = WkT + 1024 * 1024;
  short* WoT = WvT + 1024 * 1024;

  k_cvt3<<<dim3(1024, 3), dim3(256), 0, stream>>>(query, key, value, qin, kin, vin);
  k_wtrans4<<<dim3(16, 16, 4), dim3(256), 0, stream>>>(Wq, Wk, Wv, Wo, WqT, WkT, WvT, WoT);
  k_qkv<<<dim3(16, 48), dim3(256), 0, stream>>>(qin, WqT, bq, bk, bv, q, k, vT);
  k_qk<<<dim3(32, 32), dim3(512), 0, stream>>>(q, k, S);
  k_posk_exp<<<dim3(4, 1024), dim3(256), 0, stream>>>(q, pos_k, rab, mask, S);
  k_posv<<<dim3(2, 1024), dim3(256), 0, stream>>>(S, pos_v, X0p);
  k_av<<<dim3(32, 32), dim3(256), 0, stream>>>(S, vT, X0p, X);
  k_oproj<<<dim3(16, 32), dim3(256), 0, stream>>>(X, WoT, bo, out);
}

// Round 17
// 296.878 us; speedup vs baseline: 1.2570x; 1.0171x over previous
//
#include <hip/hip_runtime.h>

// MultiHeadedAttention with relative position (B=2, T=1024, D=1024, H=16, DK=64)
// Pipeline: cvt(inputs->bf16), wtrans(W->bf16 [n][k]) -> fused QKV GEMM (XCD-swizzled) ->
//   k_qk: S = q@k^T (raw, bf16) -> k_posk_exp: S = exp(S + Bp + bias - 10) in place
//   (masked -> 0) -> X0p[2] = eS@pos_v halves -> X = (X0p0+X0p1+eS@v)/l -> out = X@Wo+bo.
// R17 delta vs R16: S layout transposed to [t][bh][s] so the t-batched streamers
// (posk_exp, posv) access S as contiguous per-t panels instead of 2MB-strided rows.

#define DEV __device__ __forceinline__

typedef short bf16x8 __attribute__((ext_vector_type(8)));
typedef short bf16x4 __attribute__((ext_vector_type(4)));
typedef float f32x4 __attribute__((ext_vector_type(4)));

DEV short f2b(float f) {
  unsigned u = __builtin_bit_cast(unsigned, f);
  u = (u + 0x7FFFu + ((u >> 16) & 1u)) >> 16;
  return (short)u;
}
DEV float b2f(short s) {
  unsigned u = ((unsigned)(unsigned short)s) << 16;
  return __builtin_bit_cast(float, u);
}

// S layout: [t][bh][s] -> ((t<<15) + (bh<<10) + s)
#define SIDX(bh, t, s) ((((size_t)(t)) << 15) + ((size_t)((bh) << 10)) + (size_t)(s))

#define MFMA(a, b, c) __builtin_amdgcn_mfma_f32_16x16x32_bf16(a, b, c, 0, 0, 0)

DEV void gload16(const void* g, void* l) {
  __builtin_amdgcn_global_load_lds(
      (const __attribute__((address_space(1))) void*)g,
      (__attribute__((address_space(3))) void*)l, 16, 0, 0);
}

// ---------------------------------------------------------------------------
// P1: fp32 -> bf16 flat convert for query/key/value.
__global__ __launch_bounds__(256) void k_cvt3(
    const float* __restrict__ a, const float* __restrict__ b, const float* __restrict__ c,
    short* __restrict__ oa, short* __restrict__ ob, short* __restrict__ oc) {
  const float* src = blockIdx.y == 0 ? a : (blockIdx.y == 1 ? b : c);
  short* dst = blockIdx.y == 0 ? oa : (blockIdx.y == 1 ? ob : oc);
  size_t i = ((size_t)blockIdx.x * 256 + threadIdx.x) * 8;
  float4 p0 = *(const float4*)(src + i);
  float4 p1 = *(const float4*)(src + i + 4);
  bf16x8 o;
  o[0] = f2b(p0.x); o[1] = f2b(p0.y); o[2] = f2b(p0.z); o[3] = f2b(p0.w);
  o[4] = f2b(p1.x); o[5] = f2b(p1.y); o[6] = f2b(p1.z); o[7] = f2b(p1.w);
  *(bf16x8*)(dst + i) = o;
}

// P2: W [k][n] fp32 -> WT [n][k] bf16, 64x64 tiles via LDS.
__global__ __launch_bounds__(256) void k_wtrans4(
    const float* __restrict__ w0, const float* __restrict__ w1,
    const float* __restrict__ w2, const float* __restrict__ w3,
    short* __restrict__ o0, short* __restrict__ o1,
    short* __restrict__ o2, short* __restrict__ o3) {
  const float* src; short* dst;
  switch (blockIdx.z) {
    case 0: src = w0; dst = o0; break;
    case 1: src = w1; dst = o1; break;
    case 2: src = w2; dst = o2; break;
    default: src = w3; dst = o3;
  }
  __shared__ short LW[64][74];
  const int tid = threadIdx.x;
  const int k0 = blockIdx.y * 64, n0 = blockIdx.x * 64;
  {
    int c4 = (tid & 15) * 4;
#pragma unroll
    for (int i = 0; i < 4; ++i) {
      int r = (tid >> 4) + i * 16;
      float4 v = *(const float4*)(src + (size_t)(k0 + r) * 1024 + n0 + c4);
      LW[r][c4 + 0] = f2b(v.x); LW[r][c4 + 1] = f2b(v.y);
      LW[r][c4 + 2] = f2b(v.z); LW[r][c4 + 3] = f2b(v.w);
    }
  }
  __syncthreads();
  {
    int n = tid >> 2, kb = (tid & 3) * 16;
#pragma unroll
    for (int j2 = 0; j2 < 2; ++j2) {
      int kk = kb + j2 * 8;
      bf16x8 o;
#pragma unroll
      for (int j = 0; j < 8; ++j) o[j] = LW[kk + j][n];
      *(bf16x8*)(dst + (size_t)(n0 + n) * 1024 + k0 + kk) = o;
    }
  }
}

// ---------------------------------------------------------------------------
// K1: fused QKV projection with bijective XCD chunk-swizzle.
__global__ __launch_bounds__(256) void k_qkv(
    const short* __restrict__ Ain, const short* __restrict__ WT,
    const float* __restrict__ bq, const float* __restrict__ bk,
    const float* __restrict__ bv,
    short* __restrict__ qo, short* __restrict__ ko, short* __restrict__ vTo) {
  __shared__ short As[128 * 32];
  __shared__ short Bs[64 * 32];
  __shared__ short LW[128][72];
  const int tid = threadIdx.x;
  const int w = tid >> 6, l = tid & 63, lg = l >> 4, lr = l & 15;
  const int wm = w >> 1, wn = w & 1;
  const int flat = blockIdx.x + gridDim.x * blockIdx.y;  // 0..767
  const int flat2 = (flat & 7) * 96 + (flat >> 3);
  const int n0 = (flat2 & 15) * 64;
  const int m0 = (flat2 >> 4) * 128;
  const int seg = m0 >> 11;
  const int mseg = m0 & 2047;
  const short* Abase = Ain + ((size_t)m0 << 10);
  const short* Bbase = WT + ((size_t)seg << 20) + ((size_t)n0 << 10);
  const int srow = l >> 2, scol8 = (l & 3) * 8;
  f32x4 acc[4][2] = {};
  for (int k0 = 0; k0 < 1024; k0 += 32) {
    gload16(Abase + (size_t)((w * 2) * 16 + srow) * 1024 + k0 + scol8, &As[(w * 2) * 512]);
    gload16(Abase + (size_t)((w * 2 + 1) * 16 + srow) * 1024 + k0 + scol8, &As[(w * 2 + 1) * 512]);
    gload16(Bbase + (size_t)(w * 16 + srow) * 1024 + k0 + scol8, &Bs[w * 512]);
    __syncthreads();
    bf16x8 af[4], bf[2];
#pragma unroll
    for (int i = 0; i < 4; ++i) af[i] = *(const bf16x8*)&As[(wm * 64 + i * 16 + lr) * 32 + lg * 8];
#pragma unroll
    for (int i = 0; i < 2; ++i) bf[i] = *(const bf16x8*)&Bs[(wn * 32 + i * 16 + lr) * 32 + lg * 8];
#pragma unroll
    for (int mi = 0; mi < 4; ++mi)
#pragma unroll
      for (int ni = 0; ni < 2; ++ni) acc[mi][ni] = MFMA(af[mi], bf[ni], acc[mi][ni]);
    __syncthreads();
  }
  const float* bias = seg == 0 ? bq : (seg == 1 ? bk : bv);
  const float scale = seg == 0 ? 0.125f : 1.0f;
  float bvals[2];
#pragma unroll
  for (int ni = 0; ni < 2; ++ni) bvals[ni] = bias[n0 + wn * 32 + ni * 16 + lr];
#pragma unroll
  for (int mi = 0; mi < 4; ++mi)
#pragma unroll
    for (int ni = 0; ni < 2; ++ni)
#pragma unroll
      for (int r = 0; r < 4; ++r)
        LW[wm * 64 + mi * 16 + lg * 4 + r][wn * 32 + ni * 16 + lr] =
            f2b((acc[mi][ni][r] + bvals[ni]) * scale);
  __syncthreads();
  if (seg < 2) {
    short* dst = seg == 0 ? qo : ko;
    int r = tid >> 1, half = tid & 1;
    int m = mseg + r, b = m >> 10, t = m & 1023;
    int h = n0 >> 6;
#pragma unroll
    for (int g = 0; g < 4; ++g) {
      int dk = half * 32 + g * 8;
      bf16x8 o = *(const bf16x8*)&LW[r][dk];
      *(bf16x8*)(dst + (((size_t)(b * 16 + h) * 1024 + t) << 6) + dk) = o;
    }
  } else {
    int dkc = tid & 63, th = tid >> 6;
    int h = n0 >> 6, dk = dkc;
    int b = mseg >> 10;
    int tbase = (mseg & 1023) + th * 32;
#pragma unroll
    for (int g = 0; g < 4; ++g) {
      bf16x8 o;
#pragma unroll
      for (int e = 0; e < 8; ++e) o[e] = LW[th * 32 + g * 8 + e][dkc];
      *(bf16x8*)(vTo + (((size_t)(b * 16 + h) * 64 + dk) << 10) + tbase + g * 8) = o;
    }
  }
}

// ---------------------------------------------------------------------------
// K2a: S = q@k^T raw scores (bf16), S layout [t][bh][s].
// grid (T/32, bh); 8 waves, wave 16t x 256s.
__global__ __launch_bounds__(512, 2) void k_qk(
    const short* __restrict__ q, const short* __restrict__ kmat,
    short* __restrict__ S) {
  const int bh = blockIdx.y;
  const int tid = threadIdx.x;
  const int w = tid >> 6, l = tid & 63, lg = l >> 4, lr = l & 15;
  const int wm = w >> 2, wn = w & 3;
  const int t0 = blockIdx.x * 32 + wm * 16;
  const int scol = wn * 256;
  __shared__ short LS[8][16][266];

  bf16x8 af[2];
#pragma unroll
  for (int kk = 0; kk < 2; ++kk)
    af[kk] = *(const bf16x8*)(q + ((size_t)bh * 1024 + (t0 + lr)) * 64 + kk * 32 + lg * 8);

#pragma unroll
  for (int ni = 0; ni < 16; ++ni) {
    int s = scol + ni * 16 + lr;
    const short* kp = kmat + ((size_t)bh * 1024 + s) * 64 + lg * 8;
    f32x4 a = {};
    a = MFMA(af[0], *(const bf16x8*)kp, a);
    a = MFMA(af[1], *(const bf16x8*)(kp + 32), a);
#pragma unroll
    for (int r = 0; r < 4; ++r) LS[w][lg * 4 + r][ni * 16 + lr] = f2b(a[r]);
  }
  const int r2 = l >> 5, c16 = (l & 31) * 8;
#pragma unroll
  for (int rr = 0; rr < 8; ++rr) {
    int row = rr * 2 + r2;
    bf16x8 o = *(const bf16x8*)&LS[w][row][c16];
    *(bf16x8*)(S + SIDX(bh, t0 + row, scol + c16)) = o;
  }
}

// ---------------------------------------------------------------------------
// K2b: S = exp(S + q·pos_k + bias - 10) in place (masked -> 0). S layout [t][bh][s]:
// this block's S tile is a contiguous per-t panel region (32 bh x 64 KB span).
__global__ __launch_bounds__(256) void k_posk_exp(
    const short* __restrict__ q, const float* __restrict__ pos_k,
    const float* __restrict__ rab, const int* __restrict__ mask,
    short* __restrict__ S) {
  const int t = blockIdx.y;
  const int tid = threadIdx.x;
  const int w = tid >> 6, l = tid & 63, lg = l >> 4, lr = l & 15;
  const int sB = blockIdx.x * 256;
  const int s0 = sB + w * 64;
  __shared__ float RB[16][260];
  __shared__ int MK[2][260];
  __shared__ short SW[4][32][66];

  // ---- issue ALL independent global loads first ----
  float4 PK[4][2][2];
#pragma unroll
  for (int ni = 0; ni < 4; ++ni) {
    int s = s0 + ni * 16 + lr;
#pragma unroll
    for (int kk = 0; kk < 2; ++kk) {
      const float* pk = pos_k + ((size_t)t * 1024 + s) * 64 + kk * 32 + lg * 8;
      PK[ni][kk][0] = *(const float4*)pk;
      PK[ni][kk][1] = *(const float4*)(pk + 4);
    }
  }
  float4 rv[4];
  {
    int hr = tid >> 4, c0 = (tid & 15) * 4;
#pragma unroll
    for (int it = 0; it < 4; ++it)
      rv[it] = *(const float4*)(rab + ((size_t)hr * 1024 + t) * 1024 + sB + c0 + it * 64);
  }
  int4 mv = {1, 1, 1, 1};
  if (tid < 128) {
    int br = tid >> 6, c = (tid & 63) * 4;
    mv = *(const int4*)(mask + ((size_t)br * 1024 + t) * 1024 + sB + c);
  }
  // ---- stage to LDS ----
  {
    int hr = tid >> 4, c0 = (tid & 15) * 4;
#pragma unroll
    for (int it = 0; it < 4; ++it) {
      int c = c0 + it * 64;
      RB[hr][c] = rv[it].x; RB[hr][c + 1] = rv[it].y;
      RB[hr][c + 2] = rv[it].z; RB[hr][c + 3] = rv[it].w;
    }
  }
  if (tid < 128) {
    int br = tid >> 6, c = (tid & 63) * 4;
    MK[br][c] = mv.x; MK[br][c + 1] = mv.y; MK[br][c + 2] = mv.z; MK[br][c + 3] = mv.w;
  }
  {  // stage this wave's S tile (wave-private region); [t][bh][s] panel
#pragma unroll
    for (int rr = 0; rr < 4; ++rr) {
      int row = (l >> 3) + rr * 8;  // bh
      int s8 = (l & 7) * 8;
      *(bf16x8*)&SW[w][row][s8] = *(const bf16x8*)(S + SIDX(row, t, s0 + s8));
    }
  }
  // ---- compute: cvt + MFMA from registers ----
  bf16x8 af[2][2];
#pragma unroll
  for (int mi = 0; mi < 2; ++mi)
#pragma unroll
    for (int kk = 0; kk < 2; ++kk) {
      int bh = mi * 16 + lr;
      af[mi][kk] = *(const bf16x8*)(q + ((size_t)bh * 1024 + t) * 64 + kk * 32 + lg * 8);
    }
  f32x4 acc[2][4] = {};
#pragma unroll
  for (int ni = 0; ni < 4; ++ni) {
#pragma unroll
    for (int kk = 0; kk < 2; ++kk) {
      bf16x8 bfr;
      bfr[0] = f2b(PK[ni][kk][0].x); bfr[1] = f2b(PK[ni][kk][0].y);
      bfr[2] = f2b(PK[ni][kk][0].z); bfr[3] = f2b(PK[ni][kk][0].w);
      bfr[4] = f2b(PK[ni][kk][1].x); bfr[5] = f2b(PK[ni][kk][1].y);
      bfr[6] = f2b(PK[ni][kk][1].z); bfr[7] = f2b(PK[ni][kk][1].w);
#pragma unroll
      for (int mi = 0; mi < 2; ++mi) acc[mi][ni] = MFMA(af[mi][kk], bfr, acc[mi][ni]);
    }
  }
  __syncthreads();
#pragma unroll
  for (int ni = 0; ni < 4; ++ni) {
    int colw = w * 64 + ni * 16 + lr;
    int col = ni * 16 + lr;
    int msk0 = MK[0][colw];
    int msk1 = MK[1][colw];
#pragma unroll
    for (int r = 0; r < 4; ++r) {
      int h = lg * 4 + r;
      float bv = RB[h][colw];
      float v0 = acc[0][ni][r] + bv + b2f(SW[w][h][col]);
      float v1 = acc[1][ni][r] + bv + b2f(SW[w][16 + h][col]);
      float e0 = (msk0 == 0) ? 0.f : __expf(v0 - 10.f);
      float e1 = (msk1 == 0) ? 0.f : __expf(v1 - 10.f);
      SW[w][h][col] = f2b(e0);
      SW[w][16 + h][col] = f2b(e1);
    }
  }
#pragma unroll
  for (int rr = 0; rr < 4; ++rr) {
    int row = (l >> 3) + rr * 8;
    int s8 = (l & 7) * 8;
    bf16x8 o = *(const bf16x8*)&SW[w][row][s8];
    *(bf16x8*)(S + SIDX(row, t, s0 + s8)) = o;
  }
}

// ---------------------------------------------------------------------------
// K3: X0p[half] = fp32(eS[:, t, half-s] @ pos_v[t, half-s]). grid (2, T); 4 waves.
// S reads are now contiguous per-t panel rows ([t][bh][s]).
__global__ __launch_bounds__(256) void k_posv(
    const short* __restrict__ S, const float* __restrict__ pos_v,
    float* __restrict__ X0p) {
  const int half = blockIdx.x;
  const int t = blockIdx.y;
  const int tid = threadIdx.x;
  const int w = tid >> 6, l = tid & 63, lg = l >> 4, lr = l & 15;
  const int mi = w >> 1;
  const int nb = (w & 1) * 2;
  __shared__ short pvT[2][64][132];
  f32x4 acc[2] = {};
  const int spair = tid >> 4;
  const int dk4 = (tid & 15) * 4;
  const int sbase = half * 512;
  float4 ra[4], rb[4];
  // preload + write chunk 0
#pragma unroll
  for (int it = 0; it < 4; ++it) {
    int srel = spair * 2 + it * 32;
    const float* p0 = pos_v + ((size_t)t * 1024 + sbase + srel) * 64 + dk4;
    ra[it] = *(const float4*)p0;
    rb[it] = *(const float4*)(p0 + 64);
  }
#pragma unroll
  for (int it = 0; it < 4; ++it) {
    int srel = spair * 2 + it * 32;
    unsigned u0 = (unsigned)(unsigned short)f2b(ra[it].x) | ((unsigned)(unsigned short)f2b(rb[it].x) << 16);
    unsigned u1 = (unsigned)(unsigned short)f2b(ra[it].y) | ((unsigned)(unsigned short)f2b(rb[it].y) << 16);
    unsigned u2 = (unsigned)(unsigned short)f2b(ra[it].z) | ((unsigned)(unsigned short)f2b(rb[it].z) << 16);
    unsigned u3 = (unsigned)(unsigned short)f2b(ra[it].w) | ((unsigned)(unsigned short)f2b(rb[it].w) << 16);
    *(unsigned*)&pvT[0][dk4 + 0][srel] = u0;
    *(unsigned*)&pvT[0][dk4 + 1][srel] = u1;
    *(unsigned*)&pvT[0][dk4 + 2][srel] = u2;
    *(unsigned*)&pvT[0][dk4 + 3][srel] = u3;
  }
  __syncthreads();
  const int bh = mi * 16 + lr;
  const short* sRow = S + SIDX(bh, t, sbase);
  for (int c = 0; c < 4; ++c) {
    const int cur = c & 1;
    if (c < 3) {  // issue next chunk's loads (in flight during MFMA)
#pragma unroll
      for (int it = 0; it < 4; ++it) {
        int srel = spair * 2 + it * 32;
        const float* p0 = pos_v + ((size_t)t * 1024 + sbase + (c + 1) * 128 + srel) * 64 + dk4;
        ra[it] = *(const float4*)p0;
        rb[it] = *(const float4*)(p0 + 64);
      }
    }
    const short* sBp = sRow + c * 128;
#pragma unroll
    for (int kk = 0; kk < 4; ++kk) {
      bf16x8 afr = *(const bf16x8*)(sBp + kk * 32 + lg * 8);
#pragma unroll
      for (int ni = 0; ni < 2; ++ni) {
        int dk = (nb + ni) * 16 + lr;
        const short* pp = &pvT[cur][dk][kk * 32 + lg * 8];
        bf16x4 lo = *(const bf16x4*)pp;
        bf16x4 hi = *(const bf16x4*)(pp + 4);
        bf16x8 bfr;
        bfr[0] = lo[0]; bfr[1] = lo[1]; bfr[2] = lo[2]; bfr[3] = lo[3];
        bfr[4] = hi[0]; bfr[5] = hi[1]; bfr[6] = hi[2]; bfr[7] = hi[3];
        acc[ni] = MFMA(afr, bfr, acc[ni]);
      }
    }
    if (c < 3) {  // write next buffer (disjoint from cur; barrier before reuse)
#pragma unroll
      for (int it = 0; it < 4; ++it) {
        int srel = spair * 2 + it * 32;
        unsigned u0 = (unsigned)(unsigned short)f2b(ra[it].x) | ((unsigned)(unsigned short)f2b(rb[it].x) << 16);
        unsigned u1 = (unsigned)(unsigned short)f2b(ra[it].y) | ((unsigned)(unsigned short)f2b(rb[it].y) << 16);
        unsigned u2 = (unsigned)(unsigned short)f2b(ra[it].z) | ((unsigned)(unsigned short)f2b(rb[it].z) << 16);
        unsigned u3 = (unsigned)(unsigned short)f2b(ra[it].w) | ((unsigned)(unsigned short)f2b(rb[it].w) << 16);
        *(unsigned*)&pvT[cur ^ 1][dk4 + 0][srel] = u0;
        *(unsigned*)&pvT[cur ^ 1][dk4 + 1][srel] = u1;
        *(unsigned*)&pvT[cur ^ 1][dk4 + 2][srel] = u2;
        *(unsigned*)&pvT[cur ^ 1][dk4 + 3][srel] = u3;
      }
      __syncthreads();
    }
  }
#pragma unroll
  for (int ni = 0; ni < 2; ++ni)
#pragma unroll
    for (int r = 0; r < 4; ++r) {
      int bh2 = mi * 16 + lg * 4 + r;
      int b = bh2 >> 4, h = bh2 & 15;
      int dk = (nb + ni) * 16 + lr;
      X0p[((size_t)half << 21) + ((size_t)(b * 1024 + t)) * 1024 + h * 64 + dk] =
          acc[ni][r];
    }
}

// ---------------------------------------------------------------------------
// K4: X = bf16((X0p0 + X0p1 + eS @ v) / l), l = row-sum of eS computed inline.
// S reads per-lane t-rows in [t][bh][s] layout (2 KB contiguous per row).
__global__ __launch_bounds__(256) void k_av(
    const short* __restrict__ S, const short* __restrict__ vT,
    const float* __restrict__ X0p, short* __restrict__ X) {
  const int bh = blockIdx.y;
  const int tt0 = blockIdx.x * 32;
  const int tid = threadIdx.x;
  const int w = tid >> 6, l = tid & 63, lg = l >> 4, lr = l & 15;
  const int wm = w >> 1, wn = w & 1;
  const short* vbase = vT + ((size_t)bh << 16) + ((size_t)(wn * 32) << 10);
  const short* sbase = S + SIDX(bh, tt0 + wm * 16 + lr, 0);
  f32x4 acc[2] = {};
  float lsum = 0.f;
#pragma unroll 8
  for (int kk = 0; kk < 32; ++kk) {
    bf16x8 afr = *(const bf16x8*)(sbase + kk * 32 + lg * 8);
#pragma unroll
    for (int j = 0; j < 8; ++j) lsum += b2f(afr[j]);
#pragma unroll
    for (int ni = 0; ni < 2; ++ni) {
      bf16x8 bfr = *(const bf16x8*)(vbase + ((size_t)(ni * 16 + lr) << 10) + kk * 32 + lg * 8);
      acc[ni] = MFMA(afr, bfr, acc[ni]);
    }
  }
  lsum += __shfl_xor(lsum, 16);
  lsum += __shfl_xor(lsum, 32);
  const int b = bh >> 4, h = bh & 15;
#pragma unroll
  for (int ni = 0; ni < 2; ++ni)
#pragma unroll
    for (int r = 0; r < 4; ++r) {
      float lrow = __shfl(lsum, lg * 4 + r);
      float inv = 1.0f / lrow;
      int tt = tt0 + wm * 16 + lg * 4 + r;
      int d = h * 64 + wn * 32 + ni * 16 + lr;
      size_t idx = ((size_t)(b * 1024 + tt)) * 1024 + d;
      X[idx] = f2b((X0p[idx] + X0p[idx + (1u << 21)] + acc[ni][r]) * inv);
    }
}

// ---------------------------------------------------------------------------
// K5: out = X @ Wo + bo (fp32). 64x64 tile, BK=32, grid (16,32).
__global__ __launch_bounds__(256) void k_oproj(
    const short* __restrict__ X, const short* __restrict__ WT,
    const float* __restrict__ bias, float* __restrict__ out) {
  __shared__ short As[64 * 32];
  __shared__ short Bs[64 * 32];
  const int tid = threadIdx.x;
  const int w = tid >> 6, l = tid & 63, lg = l >> 4, lr = l & 15;
  const int wm = w >> 1, wn = w & 1;
  const int n0 = blockIdx.x * 64;
  const int m0 = blockIdx.y * 64;
  const short* Abase = X + ((size_t)m0 << 10);
  const short* Bbase = WT + ((size_t)n0 << 10);
  const int srow = l >> 2, scol8 = (l & 3) * 8;
  f32x4 acc[2][2] = {};
  for (int k0 = 0; k0 < 1024; k0 += 32) {
    gload16(Abase + (size_t)(w * 16 + srow) * 1024 + k0 + scol8, &As[w * 512]);
    gload16(Bbase + (size_t)(w * 16 + srow) * 1024 + k0 + scol8, &Bs[w * 512]);
    __syncthreads();
    bf16x8 af[2], bf[2];
#pragma unroll
    for (int i = 0; i < 2; ++i) af[i] = *(const bf16x8*)&As[(wm * 32 + i * 16 + lr) * 32 + lg * 8];
#pragma unroll
    for (int i = 0; i < 2; ++i) bf[i] = *(const bf16x8*)&Bs[(wn * 32 + i * 16 + lr) * 32 + lg * 8];
#pragma unroll
    for (int mi = 0; mi < 2; ++mi)
#pragma unroll
      for (int ni = 0; ni < 2; ++ni) acc[mi][ni] = MFMA(af[mi], bf[ni], acc[mi][ni]);
    __syncthreads();
  }
  float bvals[2];
#pragma unroll
  for (int ni = 0; ni < 2; ++ni) bvals[ni] = bias[n0 + wn * 32 + ni * 16 + lr];
#pragma unroll
  for (int mi = 0; mi < 2; ++mi)
#pragma unroll
    for (int ni = 0; ni < 2; ++ni)
#pragma unroll
      for (int r = 0; r < 4; ++r) {
        int m = m0 + wm * 32 + mi * 16 + lg * 4 + r;
        int n = n0 + wn * 32 + ni * 16 + lr;
        out[(size_t)m * 1024 + n] = acc[mi][ni][r] + bvals[ni];
      }
}

// ---------------------------------------------------------------------------
extern "C" void kernel_launch(void* const* d_in, const int* in_sizes, int n_in,
                              void* d_out, int out_size, void* d_ws, size_t ws_size,
                              hipStream_t stream) {
  (void)in_sizes; (void)n_in; (void)out_size; (void)ws_size;
  const float* query = (const float*)d_in[0];
  const float* key   = (const float*)d_in[1];
  const float* value = (const float*)d_in[2];
  const float* pos_k = (const float*)d_in[3];
  const float* pos_v = (const float*)d_in[4];
  const int*   mask  = (const int*)d_in[5];
  const float* rab   = (const float*)d_in[6];
  const float* Wq = (const float*)d_in[7];
  const float* bq = (const float*)d_in[8];
  const float* Wk = (const float*)d_in[9];
  const float* bk = (const float*)d_in[10];
  const float* Wv = (const float*)d_in[11];
  const float* bv = (const float*)d_in[12];
  const float* Wo = (const float*)d_in[13];
  const float* bo = (const float*)d_in[14];
  float* out = (float*)d_out;

  const size_t M2 = 2ull * 1024 * 1024;  // B*T*D elements
  short* q   = (short*)d_ws;
  short* k   = q + M2;
  short* vT  = k + M2;                    // [bh][dk][t]
  short* S   = vT + M2;                   // 32M bf16, layout [t][bh][s]
  float* X0p = (float*)(S + 32ull * 1024 * 1024);  // 2 halves x 2M f32 (16 MB)
  short* X   = (short*)(X0p + 2 * M2);
  short* qin = X + M2;                    // stacked [3][2048][1024]
  short* kin = qin + M2;
  short* vin = kin + M2;
  short* WqT = vin + M2;                  // stacked [3+1][1024][1024]
  short* WkT = WqT + 1024 * 1024;
  short* WvT = WkT + 1024 * 1024;
  short* WoT = WvT + 1024 * 1024;

  k_cvt3<<<dim3(1024, 3), dim3(256), 0, stream>>>(query, key, value, qin, kin, vin);
  k_wtrans4<<<dim3(16, 16, 4), dim3(256), 0, stream>>>(Wq, Wk, Wv, Wo, WqT, WkT, WvT, WoT);
  k_qkv<<<dim3(16, 48), dim3(256), 0, stream>>>(qin, WqT, bq, bk, bv, q, k, vT);
  k_qk<<<dim3(32, 32), dim3(512), 0, stream>>>(q, k, S);
  k_posk_exp<<<dim3(4, 1024), dim3(256), 0, stream>>>(q, pos_k, rab, mask, S);
  k_posv<<<dim3(2, 1024), dim3(256), 0, stream>>>(S, pos_v, X0p);
  k_av<<<dim3(32, 32), dim3(256), 0, stream>>>(S, vT, X0p, X);
  k_oproj<<<dim3(16, 32), dim3(256), 0, stream>>>(X, WoT, bo, out);
}